// Round 1
// baseline (3457.367 us; speedup 1.0000x reference)
//
#include <hip/hip_runtime.h>
#include <hip/hip_bf16.h>
#include <cstdint>
#include <cstddef>

typedef _Float16 half8  __attribute__((ext_vector_type(8)));
typedef _Float16 half4v __attribute__((ext_vector_type(4)));
typedef float    floatx4 __attribute__((ext_vector_type(4)));

#define S_LEN 200
#define BATCH 2048
#define HID   128
#define G4    512
#define T_LEN 50
#define IN_D  44

// ---- workspace byte offsets (total ~115 MB) ----
#define WS_YS    0ull
#define WS_ENCW  104857600ull   // ys: 200*2048*128 f16 = 104,857,600 B
#define WS_DECW  105840640ull   // encw: 491,520 f16 = 983,040 B
#define WS_HENC  106835968ull   // decw: 497,664 f16 = 995,328 B
#define WS_CENC  111030272ull   // h_enc: 4*2048*128 f32 = 4,194,304 B
// c_enc ends at 115,224,576

// encw/decw internal layout (f16 elements):
//   W0  [512][64]      @ +0       (K=44 zero-padded to 64)
//   WR  [3][512][128]  @ +32768
//   WH  [4][512][128]  @ +229376
//   FCW [48][128]      @ +491520  (decw only)

__device__ __forceinline__ float sigf(float x){ return 1.f/(1.f + __expf(-x)); }
__device__ __forceinline__ float tanhf_fast(float x){
  x = fminf(fmaxf(x, -15.f), 15.f);
  float e = __expf(2.f*x);
  return (e - 1.f) / (e + 1.f);
}

__global__ void prep_weights(const float* __restrict__ eW0, const float* __restrict__ eWR,
                             const float* __restrict__ eWH, const float* __restrict__ dW0,
                             const float* __restrict__ dWR, const float* __restrict__ dWH,
                             const float* __restrict__ fcW,
                             _Float16* __restrict__ encw, _Float16* __restrict__ decw)
{
  int i = blockIdx.x*256 + threadIdx.x;
  if (i < 491520) {
    _Float16 v;
    if (i < 32768)      { int j=i>>6, k=i&63; v = (k<IN_D)? (_Float16)eW0[j*IN_D+k] : (_Float16)0.f; }
    else if (i < 229376){ v = (_Float16)eWR[i-32768]; }
    else                { v = (_Float16)eWH[i-229376]; }
    encw[i] = v;
  }
  if (i < 497664) {
    _Float16 v;
    if (i < 32768)      { int j=i>>6, k=i&63; v = (k<IN_D)? (_Float16)dW0[j*IN_D+k] : (_Float16)0.f; }
    else if (i < 229376){ v = (_Float16)dWR[i-32768]; }
    else if (i < 491520){ v = (_Float16)dWH[i-229376]; }
    else { int r=i-491520; int j=r>>7, k=r&127; v = (j<IN_D)? (_Float16)fcW[j*HID+k] : (_Float16)0.f; }
    decw[i] = v;
  }
}

// Encoder layer scan: 256 blocks x 512 threads, 8 batch rows/block (M=16 MFMA
// tile, rows 8..15 zero-padded). Weight fragments register-resident.
__global__ __launch_bounds__(512, 2)
void enc_scan(const float* __restrict__ x, _Float16* __restrict__ ys,
              const _Float16* __restrict__ wih, const _Float16* __restrict__ whh,
              const float* __restrict__ bias, float* __restrict__ h_out,
              float* __restrict__ c_out, const int layer)
{
  const int tid = threadIdx.x;
  const int w = tid >> 6, lane = tid & 63, quad = lane >> 4, n16 = lane & 15;
  const int r0 = blockIdx.x * 8;
  const int KSX = (layer == 0) ? 2 : 4;
  const int K   = KSX * 32;

  __shared__ _Float16 xbuf[16][136];   // stride 136 breaks LDS bank aliasing
  __shared__ _Float16 hbuf[16][136];
  __shared__ float    gbufT[512][18];  // [gate_col][row], pad 18 for b64 access

  for (int idx = tid; idx < 16*136; idx += 512){
    ((_Float16*)xbuf)[idx] = (_Float16)0.f;
    ((_Float16*)hbuf)[idx] = (_Float16)0.f;
  }

  const int u = tid & 127, rq = tid >> 7;   // cell-update ownership: (u, rows rq*4..rq*4+3)
  float creg[4] = {0.f,0.f,0.f,0.f};
  float breg[4];
  #pragma unroll
  for (int g = 0; g < 4; ++g) breg[g] = bias[g*HID + u];

  const int jb = w * 64;                    // wave owns 64 gate columns
  half8 wfi[4][4], wfh[4][4];
  #pragma unroll
  for (int nt = 0; nt < 4; ++nt){
    const int row = jb + nt*16 + n16;
    #pragma unroll
    for (int ks = 0; ks < 4; ++ks){
      if (ks < KSX) wfi[nt][ks] = *(const half8*)(wih + (size_t)row*K + ks*32 + quad*8);
      wfh[nt][ks] = *(const half8*)(whh + (size_t)row*HID + ks*32 + quad*8);
    }
  }
  __syncthreads();

  #pragma unroll 1
  for (int t = 0; t < S_LEN; ++t){
    // ---- stage x_t into LDS (rows 0..7) ----
    if (layer == 0){
      for (int idx = tid; idx < 8*64; idx += 512){
        int r = idx >> 6, k = idx & 63;
        xbuf[r][k] = (k < IN_D) ? (_Float16)x[((size_t)(r0+r)*S_LEN + t)*IN_D + k] : (_Float16)0.f;
      }
    } else {
      if (tid < 256){
        int flat = tid * 4, r = flat >> 7, k = flat & 127;
        *(half4v*)&xbuf[r][k] = *(const half4v*)(ys + ((size_t)t*BATCH + r0 + r)*HID + k);
      }
    }
    __syncthreads();

    // ---- gates = x@Wih^T + h@Whh^T via MFMA ----
    half8 ax[4], ah[4];
    #pragma unroll
    for (int ks = 0; ks < 4; ++ks){
      if (ks < KSX) ax[ks] = *(const half8*)&xbuf[n16][ks*32 + quad*8];
      ah[ks] = *(const half8*)&hbuf[n16][ks*32 + quad*8];
    }
    #pragma unroll
    for (int nt = 0; nt < 4; ++nt){
      floatx4 acc = {0.f,0.f,0.f,0.f};
      #pragma unroll
      for (int ks = 0; ks < 4; ++ks){
        if (ks < KSX) acc = __builtin_amdgcn_mfma_f32_16x16x32_f16(ax[ks], wfi[nt][ks], acc, 0,0,0);
        acc = __builtin_amdgcn_mfma_f32_16x16x32_f16(ah[ks], wfh[nt][ks], acc, 0,0,0);
      }
      const int j = jb + nt*16 + n16;     // D: col=lane&15 (gate), row=quad*4+reg (batch)
      float2 lo; lo.x = acc[0]; lo.y = acc[1];
      float2 hi; hi.x = acc[2]; hi.y = acc[3];
      *(float2*)&gbufT[j][quad*4 + 0] = lo;
      *(float2*)&gbufT[j][quad*4 + 2] = hi;
    }
    __syncthreads();

    // ---- cell update (fp32), valid rows 0..7 ----
    if (rq < 2){
      #pragma unroll
      for (int rr = 0; rr < 4; ++rr){
        const int r = rq*4 + rr;
        float ip = gbufT[      u][r] + breg[0];
        float fp = gbufT[128 + u][r] + breg[1];
        float gp = gbufT[256 + u][r] + breg[2];
        float op = gbufT[384 + u][r] + breg[3];
        float i = sigf(ip), f = sigf(fp), g = tanhf_fast(gp), o = sigf(op);
        float c = f*creg[rr] + i*g;
        float h = o * tanhf_fast(c);
        creg[rr] = c;
        hbuf[r][u] = (_Float16)h;
        if (t == S_LEN-1){
          h_out[(size_t)(r0+r)*HID + u] = h;
          c_out[(size_t)(r0+r)*HID + u] = c;
        }
      }
    }
    __syncthreads();

    // ---- write ys[t] (consumed by next layer); last layer skips ----
    if (layer < 3 && tid < 256){
      int flat = tid * 4, r = flat >> 7, k = flat & 127;
      *(half4v*)(ys + ((size_t)t*BATCH + r0 + r)*HID + k) = *(const half4v*)&hbuf[r][k];
    }
  }
}

// Decoder: 128 blocks x 512 threads, 16 rows/block, full 4-layer stack + FC +
// feedback per block. Weights stream from L2 (f16) each (t,layer).
__global__ __launch_bounds__(512, 2)
void dec_scan(const float* __restrict__ x, const float* __restrict__ h_enc,
              const float* __restrict__ c_enc, const _Float16* __restrict__ decw,
              const float* __restrict__ dec_b, const float* __restrict__ fc_b,
              float* __restrict__ out)
{
  const int tid = threadIdx.x;
  const int w = tid >> 6, lane = tid & 63, quad = lane >> 4, n16 = lane & 15;
  const int r0 = blockIdx.x * 16;

  __shared__ _Float16 obuf[16][72];       // fed-back output, K padded to 64
  __shared__ _Float16 hbuf4[4][16][136];
  __shared__ float    gbufT[512][18];
  __shared__ float    fcb[48];

  const _Float16* DW0 = decw;
  const _Float16* DWR = decw + 32768;
  const _Float16* DWH = decw + 229376;
  const _Float16* FCW = decw + 491520;

  const int u = tid & 127, rq = tid >> 7;

  float creg[4][4];   // [layer][row] cell state in registers
  float breg[4][4];   // [layer][gate] biases for unit u
  #pragma unroll
  for (int l = 0; l < 4; ++l){
    #pragma unroll
    for (int rr = 0; rr < 4; ++rr)
      creg[l][rr] = c_enc[((size_t)l*BATCH + r0 + rq*4 + rr)*HID + u];
    #pragma unroll
    for (int g = 0; g < 4; ++g) breg[l][g] = dec_b[l*G4 + g*HID + u];
  }
  for (int idx = tid; idx < 4*16*HID; idx += 512){
    int l = idx >> 11, rem = idx & 2047, r = rem >> 7, k = rem & 127;
    hbuf4[l][r][k] = (_Float16)h_enc[((size_t)l*BATCH + r0 + r)*HID + k];
  }
  for (int idx = tid; idx < 16*72; idx += 512) ((_Float16*)obuf)[idx] = (_Float16)0.f;
  if (tid < 48) fcb[tid] = (tid < IN_D) ? fc_b[tid] : 0.f;
  __syncthreads();
  for (int idx = tid; idx < 16*IN_D; idx += 512){
    int r = idx / IN_D, k = idx % IN_D;
    obuf[r][k] = (_Float16)x[((size_t)(r0+r)*S_LEN + (S_LEN-1))*IN_D + k];
  }
  half8 wfc[4];                           // FC fragments resident (waves 0..2)
  if (w < 3){
    #pragma unroll
    for (int ks = 0; ks < 4; ++ks)
      wfc[ks] = *(const half8*)(FCW + (size_t)(w*16 + n16)*HID + ks*32 + quad*8);
  }
  __syncthreads();

  const int jb = w * 64;
  #pragma unroll 1
  for (int t = 0; t < T_LEN; ++t){
    #pragma unroll 1
    for (int l = 0; l < 4; ++l){
      const _Float16* wih = (l == 0) ? DW0 : (DWR + (size_t)(l-1)*65536);
      const _Float16* whh = DWH + (size_t)l*65536;
      const int KSX = (l == 0) ? 2 : 4;
      const int K   = KSX * 32;

      half8 wfi[4][4], wfh[4][4];
      #pragma unroll
      for (int nt = 0; nt < 4; ++nt){
        const int row = jb + nt*16 + n16;
        #pragma unroll
        for (int ks = 0; ks < 4; ++ks){
          if (ks < KSX) wfi[nt][ks] = *(const half8*)(wih + (size_t)row*K + ks*32 + quad*8);
          wfh[nt][ks] = *(const half8*)(whh + (size_t)row*HID + ks*32 + quad*8);
        }
      }
      half8 ax[4], ah[4];
      #pragma unroll
      for (int ks = 0; ks < 4; ++ks){
        if (ks < KSX){
          ax[ks] = (l == 0) ? *(const half8*)&obuf[n16][ks*32 + quad*8]
                            : *(const half8*)&hbuf4[l-1][n16][ks*32 + quad*8];
        }
        ah[ks] = *(const half8*)&hbuf4[l][n16][ks*32 + quad*8];
      }
      #pragma unroll
      for (int nt = 0; nt < 4; ++nt){
        floatx4 acc = {0.f,0.f,0.f,0.f};
        #pragma unroll
        for (int ks = 0; ks < 4; ++ks){
          if (ks < KSX) acc = __builtin_amdgcn_mfma_f32_16x16x32_f16(ax[ks], wfi[nt][ks], acc, 0,0,0);
          acc = __builtin_amdgcn_mfma_f32_16x16x32_f16(ah[ks], wfh[nt][ks], acc, 0,0,0);
        }
        const int j = jb + nt*16 + n16;
        float2 lo; lo.x = acc[0]; lo.y = acc[1];
        float2 hi; hi.x = acc[2]; hi.y = acc[3];
        *(float2*)&gbufT[j][quad*4 + 0] = lo;
        *(float2*)&gbufT[j][quad*4 + 2] = hi;
      }
      __syncthreads();

      #pragma unroll
      for (int rr = 0; rr < 4; ++rr){
        const int r = rq*4 + rr;
        float ip = gbufT[      u][r] + breg[l][0];
        float fp = gbufT[128 + u][r] + breg[l][1];
        float gp = gbufT[256 + u][r] + breg[l][2];
        float op = gbufT[384 + u][r] + breg[l][3];
        float i = sigf(ip), f = sigf(fp), g = tanhf_fast(gp), o = sigf(op);
        float c = f*creg[l][rr] + i*g;
        float h = o * tanhf_fast(c);
        creg[l][rr] = c;
        hbuf4[l][r][u] = (_Float16)h;
      }
      __syncthreads();
    }
    // ---- FC + feedback: out = h3 @ fcW^T + fcb ----
    if (w < 3){
      half8 a3[4];
      #pragma unroll
      for (int ks = 0; ks < 4; ++ks) a3[ks] = *(const half8*)&hbuf4[3][n16][ks*32 + quad*8];
      floatx4 acc = {0.f,0.f,0.f,0.f};
      #pragma unroll
      for (int ks = 0; ks < 4; ++ks) acc = __builtin_amdgcn_mfma_f32_16x16x32_f16(a3[ks], wfc[ks], acc, 0,0,0);
      const int j = w*16 + n16;
      if (j < IN_D){
        #pragma unroll
        for (int reg = 0; reg < 4; ++reg){
          const int r = quad*4 + reg;
          float v = acc[reg] + fcb[j];
          out[((size_t)(r0 + r)*T_LEN + t)*IN_D + j] = v;
          obuf[r][j] = (_Float16)v;
        }
      }
    }
    __syncthreads();
  }
}

extern "C" void kernel_launch(void* const* d_in, const int* in_sizes, int n_in,
                              void* d_out, int out_size, void* d_ws, size_t ws_size,
                              hipStream_t stream)
{
  const float* x        = (const float*)d_in[0];
  // d_in[1] = target (unused)
  const float* enc_Wih0 = (const float*)d_in[2];
  const float* enc_WihR = (const float*)d_in[3];
  const float* enc_Whh  = (const float*)d_in[4];
  const float* enc_b    = (const float*)d_in[5];
  const float* dec_Wih0 = (const float*)d_in[6];
  const float* dec_WihR = (const float*)d_in[7];
  const float* dec_Whh  = (const float*)d_in[8];
  const float* dec_b    = (const float*)d_in[9];
  const float* fc_W     = (const float*)d_in[10];
  const float* fc_b     = (const float*)d_in[11];

  char* ws = (char*)d_ws;
  _Float16* ys   = (_Float16*)(ws + WS_YS);
  _Float16* encw = (_Float16*)(ws + WS_ENCW);
  _Float16* decw = (_Float16*)(ws + WS_DECW);
  float* h_enc   = (float*)(ws + WS_HENC);
  float* c_enc   = (float*)(ws + WS_CENC);
  float* outp    = (float*)d_out;

  prep_weights<<<1944, 256, 0, stream>>>(enc_Wih0, enc_WihR, enc_Whh,
                                         dec_Wih0, dec_WihR, dec_Whh, fc_W,
                                         encw, decw);
  for (int l = 0; l < 4; ++l){
    const _Float16* wih = (l == 0) ? encw : (encw + 32768 + (size_t)(l-1)*65536);
    const _Float16* whh = encw + 229376 + (size_t)l*65536;
    enc_scan<<<256, 512, 0, stream>>>(x, ys, wih, whh, enc_b + l*G4,
                                      h_enc + (size_t)l*BATCH*HID,
                                      c_enc + (size_t)l*BATCH*HID, l);
  }
  dec_scan<<<128, 512, 0, stream>>>(x, h_enc, c_enc, decw, dec_b, fc_b, outp);
}

// Round 2
// 3373.453 us; speedup vs baseline: 1.0249x; 1.0249x over previous
//
#include <hip/hip_runtime.h>
#include <hip/hip_bf16.h>
#include <cstdint>
#include <cstddef>

typedef _Float16 half8  __attribute__((ext_vector_type(8)));
typedef float    floatx4 __attribute__((ext_vector_type(4)));

#define S_LEN 200
#define BATCH 2048
#define HID   128
#define T_LEN 50
#define IN_D  44

// ---- workspace byte offsets (total ~24.5 MB) ----
// encw/decw layout (f16 elems): W0 [512][64] @0 (K padded 44->64),
//   WR [3][512][128] @32768, WH [4][512][128] @229376, FCW [48][128] @491520 (dec only)
#define OFF_ENCW   0ull
#define OFF_DECW   983040ull
#define OFF_RING_E 1978368ull    // [3][8][2048][128] f16 = 12,582,912 B
#define OFF_RING_D 14561280ull   // [3][2][2048][128] f16 = 3,145,728 B
#define OFF_ORING  17707008ull   // [2][2048][64] f16 = 524,288 B
#define OFF_HENC   18231296ull   // [4][2048][128] f16 = 2,097,152 B
#define OFF_CENC   20328448ull   // [4][2048][128] f32 = 4,194,304 B
#define OFF_FLAGS  24522752ull   // int[512]: [0..255]=enc (l*64+s), [256..511]=dec

__device__ __forceinline__ float sigf(float x){ return 1.f/(1.f + __expf(-x)); }
__device__ __forceinline__ float tanhf_fast(float x){
  x = fminf(fmaxf(x, -15.f), 15.f);
  float e = __expf(2.f*x);
  return (e - 1.f) / (e + 1.f);
}

__global__ void prep_weights(const float* __restrict__ eW0, const float* __restrict__ eWR,
                             const float* __restrict__ eWH, const float* __restrict__ dW0,
                             const float* __restrict__ dWR, const float* __restrict__ dWH,
                             const float* __restrict__ fcW,
                             _Float16* __restrict__ encw, _Float16* __restrict__ decw,
                             _Float16* __restrict__ oring, int* __restrict__ flags)
{
  int i = blockIdx.x*256 + threadIdx.x;
  if (i < 491520) {
    _Float16 v;
    if (i < 32768)      { int j=i>>6, k=i&63; v = (k<IN_D)? (_Float16)eW0[j*IN_D+k] : (_Float16)0.f; }
    else if (i < 229376){ v = (_Float16)eWR[i-32768]; }
    else                { v = (_Float16)eWH[i-229376]; }
    encw[i] = v;
  }
  if (i < 497664) {
    _Float16 v;
    if (i < 32768)      { int j=i>>6, k=i&63; v = (k<IN_D)? (_Float16)dW0[j*IN_D+k] : (_Float16)0.f; }
    else if (i < 229376){ v = (_Float16)dWR[i-32768]; }
    else if (i < 491520){ v = (_Float16)dWH[i-229376]; }
    else { int r=i-491520; int j=r>>7, k=r&127; v = (j<IN_D)? (_Float16)fcW[j*HID+k] : (_Float16)0.f; }
    decw[i] = v;
  }
  if (i < 262144) oring[i] = (_Float16)0.f;   // zero incl. pad cols 44..63
  if (i < 512)    flags[i] = 0;
}

// ============================================================================
// Persistent pipelined LSTM scan. Grid = 4 layers x 64 slices = 256 blocks,
// 512 threads, __launch_bounds__(512,2) => VGPR<=256 => every CU can host a
// block => full grid co-resident => cross-block spin-waits are deadlock-free.
// Wave w owns hidden units u = w*16+n16; its 4 MFMA column-tiles are gates
// {i,f,g,o} of those SAME units (rows nt*128+u of W), so the cell update is
// entirely in registers (no gate transpose through LDS).
// ============================================================================

__global__ __launch_bounds__(512, 2)
void enc_pipe(const float* __restrict__ x, const _Float16* __restrict__ encw,
              const float* __restrict__ enc_b, _Float16* __restrict__ ring,
              _Float16* __restrict__ h_enc, float* __restrict__ c_enc,
              int* __restrict__ flags)
{
  const int tid = threadIdx.x;
  const int w = tid >> 6, lane = tid & 63, quad = lane >> 4, n16 = lane & 15;
  const int l = blockIdx.x >> 6, s = blockIdx.x & 63, r0 = s * 32;
  const int u = w*16 + n16;
  const int KSI = (l == 0) ? 2 : 4;

  __shared__ _Float16 xbuf[32][136];
  __shared__ _Float16 hb[2][32][136];

  for (int i = tid; i < 32*136; i += 512){
    ((_Float16*)xbuf)[i] = (_Float16)0.f;
    ((_Float16*)hb[0])[i] = (_Float16)0.f;
  }

  // register-resident weights: rows nt*128+u of [512][K]
  const _Float16* Wi = (l==0) ? encw : encw + 32768 + (size_t)(l-1)*65536;
  const _Float16* Wh = encw + 229376 + (size_t)l*65536;
  const int KI = KSI * 32;
  half8 wfi[4][4], wfh[4][4];
  #pragma unroll
  for (int nt = 0; nt < 4; ++nt){
    const int grow = nt*128 + u;
    #pragma unroll
    for (int ks = 0; ks < 4; ++ks){
      if (ks < KSI) wfi[nt][ks] = *(const half8*)(Wi + (size_t)grow*KI + ks*32 + quad*8);
      wfh[nt][ks] = *(const half8*)(Wh + (size_t)grow*HID + ks*32 + quad*8);
    }
  }
  float breg[4];
  #pragma unroll
  for (int g = 0; g < 4; ++g) breg[g] = enc_b[l*512 + g*128 + u];
  float creg[2][4] = {{0.f,0.f,0.f,0.f},{0.f,0.f,0.f,0.f}};

  // layer-0 x prefetch setup (3 elems/thread covers 32*44=1408)
  int xr_r[3], xr_k[3]; bool xr_v[3]; float xr[3];
  if (l == 0){
    #pragma unroll
    for (int j = 0; j < 3; ++j){
      int idx = tid + j*512; xr_v[j] = idx < 32*IN_D;
      xr_r[j] = xr_v[j] ? idx / IN_D : 0; xr_k[j] = xr_v[j] ? idx % IN_D : 0;
      xr[j] = xr_v[j] ? x[((size_t)(r0+xr_r[j])*S_LEN + 0)*IN_D + xr_k[j]] : 0.f;
    }
  }

  int* flag_self = flags + l*64 + s;
  int* flag_in   = flags + (l-1)*64 + s;   // valid for l>0
  int* flag_cons = flags + (l+1)*64 + s;   // valid for l<3

  __syncthreads();

  _Float16 (*hcur)[136] = hb[0];
  _Float16 (*hnxt)[136] = hb[1];

  for (int t = 0; t < S_LEN; ++t){
    if (tid == 0){
      if (l > 0) while (atomicAdd(flag_in, 0) < t+1) {}
      if (l < 3 && t >= 8) while (atomicAdd(flag_cons, 0) < t-7) {}
      __builtin_amdgcn_fence(__ATOMIC_ACQUIRE, "agent");
    }
    __syncthreads();

    // ---- stage input ----
    if (l == 0){
      #pragma unroll
      for (int j = 0; j < 3; ++j)
        if (xr_v[j]) xbuf[xr_r[j]][xr_k[j]] = (_Float16)xr[j];
    } else {
      const _Float16* src = ring + (((size_t)(l-1)*8 + (t&7))*BATCH + r0)*HID;
      int idx = tid*8, rr_ = idx >> 7, kk = idx & 127;
      *(half8*)&xbuf[rr_][kk] = *(const half8*)(src + rr_*HID + kk);
    }
    __syncthreads();

    if (l == 0 && t < S_LEN-1){
      #pragma unroll
      for (int j = 0; j < 3; ++j)
        if (xr_v[j]) xr[j] = x[((size_t)(r0+xr_r[j])*S_LEN + (t+1))*IN_D + xr_k[j]];
    }

    // ---- 2 M-tiles: gates via MFMA, in-register cell update ----
    #pragma unroll
    for (int m = 0; m < 2; ++m){
      half8 ai[4], ah[4];
      #pragma unroll
      for (int ks = 0; ks < 4; ++ks){
        if (ks < KSI) ai[ks] = *(const half8*)&xbuf[m*16+n16][ks*32 + quad*8];
        ah[ks] = *(const half8*)&hcur[m*16+n16][ks*32 + quad*8];
      }
      floatx4 acc[4];
      #pragma unroll
      for (int nt = 0; nt < 4; ++nt){
        acc[nt] = (floatx4){0.f,0.f,0.f,0.f};
        #pragma unroll
        for (int ks = 0; ks < 4; ++ks){
          if (ks < KSI) acc[nt] = __builtin_amdgcn_mfma_f32_16x16x32_f16(ai[ks], wfi[nt][ks], acc[nt], 0,0,0);
          acc[nt] = __builtin_amdgcn_mfma_f32_16x16x32_f16(ah[ks], wfh[nt][ks], acc[nt], 0,0,0);
        }
      }
      #pragma unroll
      for (int rr = 0; rr < 4; ++rr){
        float ip = acc[0][rr] + breg[0];
        float fp = acc[1][rr] + breg[1];
        float gp = acc[2][rr] + breg[2];
        float op = acc[3][rr] + breg[3];
        float cc = sigf(fp)*creg[m][rr] + sigf(ip)*tanhf_fast(gp);
        float hh = sigf(op)*tanhf_fast(cc);
        creg[m][rr] = cc;
        const int row = m*16 + quad*4 + rr;
        hnxt[row][u] = (_Float16)hh;
        if (t == S_LEN-1){
          h_enc[((size_t)l*BATCH + r0 + row)*HID + u] = (_Float16)hh;
          c_enc[((size_t)l*BATCH + r0 + row)*HID + u] = cc;
        }
      }
    }
    __syncthreads();

    // ---- publish h to ring (layers 0..2) ----
    if (l < 3){
      _Float16* dst = ring + (((size_t)l*8 + (t&7))*BATCH + r0)*HID;
      int idx = tid*8, rr_ = idx >> 7, kk = idx & 127;
      *(half8*)(dst + rr_*HID + kk) = *(const half8*)&hnxt[rr_][kk];
      __syncthreads();
    }
    if (tid == 0){
      __builtin_amdgcn_fence(__ATOMIC_RELEASE, "agent");
      atomicExch(flag_self, t+1);
    }
    _Float16 (*tmp)[136] = hcur; hcur = hnxt; hnxt = tmp;
  }
}

__global__ __launch_bounds__(512, 2)
void dec_pipe(const float* __restrict__ x, const _Float16* __restrict__ decw,
              const float* __restrict__ dec_b, const float* __restrict__ fc_b,
              _Float16* __restrict__ ring, _Float16* __restrict__ oring,
              const _Float16* __restrict__ h_enc, const float* __restrict__ c_enc,
              int* __restrict__ flags, float* __restrict__ out)
{
  const int tid = threadIdx.x;
  const int w = tid >> 6, lane = tid & 63, quad = lane >> 4, n16 = lane & 15;
  const int l = blockIdx.x >> 6, s = blockIdx.x & 63, r0 = s * 32;
  const int u = w*16 + n16;
  const int KSI = (l == 0) ? 2 : 4;

  __shared__ _Float16 xbuf[32][136];
  __shared__ _Float16 hb[2][32][136];

  for (int i = tid; i < 32*136; i += 512) ((_Float16*)xbuf)[i] = (_Float16)0.f;

  const _Float16* Wi = (l==0) ? decw : decw + 32768 + (size_t)(l-1)*65536;
  const _Float16* Wh = decw + 229376 + (size_t)l*65536;
  const _Float16* FCW = decw + 491520;
  const int KI = KSI * 32;
  half8 wfi[4][4], wfh[4][4];
  #pragma unroll
  for (int nt = 0; nt < 4; ++nt){
    const int grow = nt*128 + u;
    #pragma unroll
    for (int ks = 0; ks < 4; ++ks){
      if (ks < KSI) wfi[nt][ks] = *(const half8*)(Wi + (size_t)grow*KI + ks*32 + quad*8);
      wfh[nt][ks] = *(const half8*)(Wh + (size_t)grow*HID + ks*32 + quad*8);
    }
  }
  float breg[4];
  #pragma unroll
  for (int g = 0; g < 4; ++g) breg[g] = dec_b[l*512 + g*128 + u];

  // init h (LDS) and c (regs) from encoder final state
  {
    int idx = tid*8, rr_ = idx >> 7, kk = idx & 127;
    *(half8*)&hb[0][rr_][kk] = *(const half8*)(h_enc + ((size_t)l*BATCH + r0)*HID + rr_*HID + kk);
  }
  float creg[2][4];
  #pragma unroll
  for (int m = 0; m < 2; ++m)
    #pragma unroll
    for (int rr = 0; rr < 4; ++rr)
      creg[m][rr] = c_enc[((size_t)l*BATCH + r0 + m*16 + quad*4 + rr)*HID + u];

  // FC fragments + bias (waves 0..2; FCW rows 44..47 are zero)
  half8 wfc[4]; float fcb_j = 0.f;
  const int j = w*16 + n16;
  if (w < 3){
    #pragma unroll
    for (int ks = 0; ks < 4; ++ks)
      wfc[ks] = *(const half8*)(FCW + (size_t)j*HID + ks*32 + quad*8);
    if (j < IN_D) fcb_j = fc_b[j];
  }

  int* flag_self = flags + 256 + l*64 + s;
  int* flag_in   = flags + 256 + (l-1)*64 + s;  // l>0
  int* flag_fc   = flags + 256 + 3*64 + s;      // l==0 waits on layer 3

  __syncthreads();

  _Float16 (*hcur)[136] = hb[0];
  _Float16 (*hnxt)[136] = hb[1];

  for (int t = 0; t < T_LEN; ++t){
    if (tid == 0){
      if (l > 0)            while (atomicAdd(flag_in, 0) < t+1) {}
      else if (t > 0)       while (atomicAdd(flag_fc, 0) < t)   {}
      __builtin_amdgcn_fence(__ATOMIC_ACQUIRE, "agent");
    }
    __syncthreads();

    // ---- stage input ----
    if (l == 0){
      if (t == 0){
        for (int idx = tid; idx < 32*IN_D; idx += 512){
          int r = idx / IN_D, k = idx % IN_D;
          xbuf[r][k] = (_Float16)x[((size_t)(r0+r)*S_LEN + (S_LEN-1))*IN_D + k];
        }
      } else {
        if (tid < 256){
          const _Float16* src = oring + ((size_t)((t-1)&1)*BATCH + r0)*64;
          int idx = tid*8, rr_ = idx >> 6, kk = idx & 63;
          *(half8*)&xbuf[rr_][kk] = *(const half8*)(src + rr_*64 + kk);
        }
      }
    } else {
      const _Float16* src = ring + (((size_t)(l-1)*2 + (t&1))*BATCH + r0)*HID;
      int idx = tid*8, rr_ = idx >> 7, kk = idx & 127;
      *(half8*)&xbuf[rr_][kk] = *(const half8*)(src + rr_*HID + kk);
    }
    __syncthreads();

    // ---- gates + cell update ----
    #pragma unroll
    for (int m = 0; m < 2; ++m){
      half8 ai[4], ah[4];
      #pragma unroll
      for (int ks = 0; ks < 4; ++ks){
        if (ks < KSI) ai[ks] = *(const half8*)&xbuf[m*16+n16][ks*32 + quad*8];
        ah[ks] = *(const half8*)&hcur[m*16+n16][ks*32 + quad*8];
      }
      floatx4 acc[4];
      #pragma unroll
      for (int nt = 0; nt < 4; ++nt){
        acc[nt] = (floatx4){0.f,0.f,0.f,0.f};
        #pragma unroll
        for (int ks = 0; ks < 4; ++ks){
          if (ks < KSI) acc[nt] = __builtin_amdgcn_mfma_f32_16x16x32_f16(ai[ks], wfi[nt][ks], acc[nt], 0,0,0);
          acc[nt] = __builtin_amdgcn_mfma_f32_16x16x32_f16(ah[ks], wfh[nt][ks], acc[nt], 0,0,0);
        }
      }
      #pragma unroll
      for (int rr = 0; rr < 4; ++rr){
        float ip = acc[0][rr] + breg[0];
        float fp = acc[1][rr] + breg[1];
        float gp = acc[2][rr] + breg[2];
        float op = acc[3][rr] + breg[3];
        float cc = sigf(fp)*creg[m][rr] + sigf(ip)*tanhf_fast(gp);
        float hh = sigf(op)*tanhf_fast(cc);
        creg[m][rr] = cc;
        hnxt[m*16 + quad*4 + rr][u] = (_Float16)hh;
      }
    }
    __syncthreads();

    if (l < 3){
      _Float16* dst = ring + (((size_t)l*2 + (t&1))*BATCH + r0)*HID;
      int idx = tid*8, rr_ = idx >> 7, kk = idx & 127;
      *(half8*)(dst + rr_*HID + kk) = *(const half8*)&hnxt[rr_][kk];
      __syncthreads();
    } else {
      // ---- FC + output + feedback (waves 0..2 cover cols 0..47) ----
      if (w < 3){
        #pragma unroll
        for (int m = 0; m < 2; ++m){
          half8 a3[4];
          #pragma unroll
          for (int ks = 0; ks < 4; ++ks) a3[ks] = *(const half8*)&hnxt[m*16+n16][ks*32 + quad*8];
          floatx4 facc = (floatx4){0.f,0.f,0.f,0.f};
          #pragma unroll
          for (int ks = 0; ks < 4; ++ks) facc = __builtin_amdgcn_mfma_f32_16x16x32_f16(a3[ks], wfc[ks], facc, 0,0,0);
          #pragma unroll
          for (int rr = 0; rr < 4; ++rr){
            const int row = m*16 + quad*4 + rr;
            float v = facc[rr] + fcb_j;
            oring[((size_t)(t&1)*BATCH + r0 + row)*64 + j] = (_Float16)v;
            if (j < IN_D)
              out[((size_t)(r0 + row)*T_LEN + t)*IN_D + j] = v;
          }
        }
      }
      __syncthreads();
    }
    if (tid == 0){
      __builtin_amdgcn_fence(__ATOMIC_RELEASE, "agent");
      atomicExch(flag_self, t+1);
    }
    _Float16 (*tmp)[136] = hcur; hcur = hnxt; hnxt = tmp;
  }
}

extern "C" void kernel_launch(void* const* d_in, const int* in_sizes, int n_in,
                              void* d_out, int out_size, void* d_ws, size_t ws_size,
                              hipStream_t stream)
{
  const float* x        = (const float*)d_in[0];
  const float* enc_Wih0 = (const float*)d_in[2];
  const float* enc_WihR = (const float*)d_in[3];
  const float* enc_Whh  = (const float*)d_in[4];
  const float* enc_b    = (const float*)d_in[5];
  const float* dec_Wih0 = (const float*)d_in[6];
  const float* dec_WihR = (const float*)d_in[7];
  const float* dec_Whh  = (const float*)d_in[8];
  const float* dec_b    = (const float*)d_in[9];
  const float* fc_W     = (const float*)d_in[10];
  const float* fc_b     = (const float*)d_in[11];

  char* ws = (char*)d_ws;
  _Float16* encw   = (_Float16*)(ws + OFF_ENCW);
  _Float16* decw   = (_Float16*)(ws + OFF_DECW);
  _Float16* ring_e = (_Float16*)(ws + OFF_RING_E);
  _Float16* ring_d = (_Float16*)(ws + OFF_RING_D);
  _Float16* oring  = (_Float16*)(ws + OFF_ORING);
  _Float16* h_enc  = (_Float16*)(ws + OFF_HENC);
  float*    c_enc  = (float*)(ws + OFF_CENC);
  int*      flags  = (int*)(ws + OFF_FLAGS);
  float*    outp   = (float*)d_out;

  prep_weights<<<1944, 256, 0, stream>>>(enc_Wih0, enc_WihR, enc_Whh,
                                         dec_Wih0, dec_WihR, dec_Whh, fc_W,
                                         encw, decw, oring, flags);
  enc_pipe<<<256, 512, 0, stream>>>(x, encw, enc_b, ring_e, h_enc, c_enc, flags);
  dec_pipe<<<256, 512, 0, stream>>>(x, decw, dec_b, fc_b, ring_d, oring,
                                    h_enc, c_enc, flags, outp);
}

// Round 4
// 2292.568 us; speedup vs baseline: 1.5081x; 1.4715x over previous
//
#include <hip/hip_runtime.h>
#include <hip/hip_bf16.h>
#include <cstdint>
#include <cstddef>

typedef _Float16 half8  __attribute__((ext_vector_type(8)));
typedef float    floatx4 __attribute__((ext_vector_type(4)));

#define S_LEN 200
#define BATCH 2048
#define HID   128
#define T_LEN 50
#define IN_D  44

// ---- workspace byte offsets ----
// encw/decw layout (f16 elems): W0 [512][64] @0 (K padded 44->64),
//   WR [3][512][128] @32768, WH [4][512][128] @229376, FCW [48][128] @491520 (dec only)
#define OFF_ENCW   0ull
#define OFF_DECW   983040ull
#define OFF_RING_E 1978368ull    // [3][8][2048][128] f16 = 12,582,912 B
#define OFF_RING_D 14561280ull   // [3][2][2048][128] f16 = 3,145,728 B
#define OFF_ORING  17707008ull   // [2][2048][64] f16 = 524,288 B
#define OFF_HENC   18231296ull   // [4][2048][128] f16 = 2,097,152 B
#define OFF_CENC   20328448ull   // [4][2048][128] f32 = 4,194,304 B
#define OFF_FLAGS  24522752ull   // int[512*32]: flag i at [i*32] (128B apart)

#define SCOPE_AGENT __HIP_MEMORY_SCOPE_AGENT

__device__ __forceinline__ float sigf(float x){ return 1.f/(1.f + __expf(-x)); }
__device__ __forceinline__ float tanhf_fast(float x){
  x = fminf(fmaxf(x, -15.f), 15.f);
  float e = __expf(2.f*x);
  return (e - 1.f) / (e + 1.f);
}

// Per-access coherent ops (global_load/store_dword sc0 sc1) — NO fences, so no
// buffer_inv / buffer_wbl2 L2 nuking (that was round 2's 3x write amplification).
__device__ __forceinline__ int  ldc(const int* p){ return __hip_atomic_load(p, __ATOMIC_RELAXED, SCOPE_AGENT); }
__device__ __forceinline__ void stc(int* p, int v){ __hip_atomic_store(p, v, __ATOMIC_RELAXED, SCOPE_AGENT); }
__device__ __forceinline__ void drain_vm(){ asm volatile("s_waitcnt vmcnt(0)" ::: "memory"); }
__device__ __forceinline__ int* flagp(int* flags, int idx){ return flags + idx*32; }

__global__ void prep_weights(const float* __restrict__ eW0, const float* __restrict__ eWR,
                             const float* __restrict__ eWH, const float* __restrict__ dW0,
                             const float* __restrict__ dWR, const float* __restrict__ dWH,
                             const float* __restrict__ fcW,
                             _Float16* __restrict__ encw, _Float16* __restrict__ decw,
                             _Float16* __restrict__ oring, int* __restrict__ flags)
{
  int i = blockIdx.x*256 + threadIdx.x;
  if (i < 491520) {
    _Float16 v;
    if (i < 32768)      { int j=i>>6, k=i&63; v = (k<IN_D)? (_Float16)eW0[j*IN_D+k] : (_Float16)0.f; }
    else if (i < 229376){ v = (_Float16)eWR[i-32768]; }
    else                { v = (_Float16)eWH[i-229376]; }
    encw[i] = v;
  }
  if (i < 497664) {
    _Float16 v;
    if (i < 32768)      { int j=i>>6, k=i&63; v = (k<IN_D)? (_Float16)dW0[j*IN_D+k] : (_Float16)0.f; }
    else if (i < 229376){ v = (_Float16)dWR[i-32768]; }
    else if (i < 491520){ v = (_Float16)dWH[i-229376]; }
    else { int r=i-491520; int j=r>>7, k=r&127; v = (j<IN_D)? (_Float16)fcW[j*HID+k] : (_Float16)0.f; }
    decw[i] = v;
  }
  if (i < 262144) oring[i] = (_Float16)0.f;   // ws is 0xAA-poisoned each launch
  if (i < 16384)  flags[i] = 0;
}

// ============================================================================
// Persistent pipelined LSTM. Grid = 4 layers x 64 slices = 256 blocks, 512 thr,
// launch_bounds(512,2) => full grid co-resident => spin-waits deadlock-free.
// Wave w owns units u=w*16+n16; its 4 N-tiles are gates {i,f,g,o} of those
// units => cell update fully in registers. Weights register-resident.
// Cross-block handoff: coherent dword ring I/O + padded flag + vmcnt drain.
// ============================================================================

__global__ __launch_bounds__(512, 2)
void enc_pipe(const float* __restrict__ x, const _Float16* __restrict__ encw,
              const float* __restrict__ enc_b, _Float16* __restrict__ ring,
              _Float16* __restrict__ h_enc, float* __restrict__ c_enc,
              int* __restrict__ flags)
{
  const int tid = threadIdx.x;
  const int w = tid >> 6, lane = tid & 63, quad = lane >> 4, n16 = lane & 15;
  const int l = blockIdx.x >> 6, s = blockIdx.x & 63, r0 = s * 32;
  const int u = w*16 + n16;
  const int KSI = (l == 0) ? 2 : 4;

  __shared__ _Float16 xbuf[32][136];
  __shared__ _Float16 hb[2][32][136];

  for (int i = tid; i < 32*136; i += 512){
    ((_Float16*)xbuf)[i] = (_Float16)0.f;
    ((_Float16*)hb[0])[i] = (_Float16)0.f;
  }

  const _Float16* Wi = (l==0) ? encw : encw + 32768 + (size_t)(l-1)*65536;
  const _Float16* Wh = encw + 229376 + (size_t)l*65536;
  const int KI = KSI * 32;
  half8 wfi[4][4], wfh[4][4];
  #pragma unroll
  for (int nt = 0; nt < 4; ++nt){
    const int grow = nt*128 + u;
    #pragma unroll
    for (int ks = 0; ks < 4; ++ks){
      if (ks < KSI) wfi[nt][ks] = *(const half8*)(Wi + (size_t)grow*KI + ks*32 + quad*8);
      wfh[nt][ks] = *(const half8*)(Wh + (size_t)grow*HID + ks*32 + quad*8);
    }
  }
  float breg[4];
  #pragma unroll
  for (int g = 0; g < 4; ++g) breg[g] = enc_b[l*512 + g*128 + u];
  float creg[2][4] = {{0.f,0.f,0.f,0.f},{0.f,0.f,0.f,0.f}};

  // layer-0 x prefetch (3 elems/thread covers 32*44=1408)
  int xr_r[3], xr_k[3]; bool xr_v[3]; float xr[3];
  if (l == 0){
    #pragma unroll
    for (int j = 0; j < 3; ++j){
      int idx = tid + j*512; xr_v[j] = idx < 32*IN_D;
      xr_r[j] = xr_v[j] ? idx / IN_D : 0; xr_k[j] = xr_v[j] ? idx % IN_D : 0;
      xr[j] = xr_v[j] ? x[((size_t)(r0+xr_r[j])*S_LEN + 0)*IN_D + xr_k[j]] : 0.f;
    }
  }

  int* flag_self = flagp(flags, l*64 + s);
  int* flag_in   = flagp(flags, (l-1)*64 + s);   // l>0
  int* flag_cons = flagp(flags, (l+1)*64 + s);   // l<3

  __syncthreads();

  _Float16 (*hcur)[136] = hb[0];
  _Float16 (*hnxt)[136] = hb[1];

  for (int t = 0; t < S_LEN; ++t){
    if (tid == 0){
      if (l > 0)           while (ldc(flag_in)   < t+1) __builtin_amdgcn_s_sleep(1);
      if (l < 3 && t >= 8) while (ldc(flag_cons) < t-7) __builtin_amdgcn_s_sleep(1);
    }
    __syncthreads();

    // ---- stage input ----
    if (l == 0){
      #pragma unroll
      for (int j = 0; j < 3; ++j)
        if (xr_v[j]) xbuf[xr_r[j]][xr_k[j]] = (_Float16)xr[j];
    } else {
      const int* src = (const int*)(ring + (((size_t)(l-1)*8 + (t&7))*BATCH + r0)*HID);
      #pragma unroll
      for (int jj = 0; jj < 4; ++jj){
        int d = tid + jj*512;                // 2048 ints = 32 rows x 64
        int v = ldc(src + d);
        *(int*)&xbuf[d>>6][(d&63)*2] = v;
      }
    }
    __syncthreads();

    if (l == 0 && t < S_LEN-1){
      #pragma unroll
      for (int j = 0; j < 3; ++j)
        if (xr_v[j]) xr[j] = x[((size_t)(r0+xr_r[j])*S_LEN + (t+1))*IN_D + xr_k[j]];
    }

    // ---- gates via MFMA + in-register cell update ----
    #pragma unroll
    for (int m = 0; m < 2; ++m){
      half8 ai[4], ah[4];
      #pragma unroll
      for (int ks = 0; ks < 4; ++ks){
        if (ks < KSI) ai[ks] = *(const half8*)&xbuf[m*16+n16][ks*32 + quad*8];
        ah[ks] = *(const half8*)&hcur[m*16+n16][ks*32 + quad*8];
      }
      floatx4 acc[4];
      #pragma unroll
      for (int nt = 0; nt < 4; ++nt){
        acc[nt] = (floatx4){0.f,0.f,0.f,0.f};
        #pragma unroll
        for (int ks = 0; ks < 4; ++ks){
          if (ks < KSI) acc[nt] = __builtin_amdgcn_mfma_f32_16x16x32_f16(ai[ks], wfi[nt][ks], acc[nt], 0,0,0);
          acc[nt] = __builtin_amdgcn_mfma_f32_16x16x32_f16(ah[ks], wfh[nt][ks], acc[nt], 0,0,0);
        }
      }
      #pragma unroll
      for (int rr = 0; rr < 4; ++rr){
        float ip = acc[0][rr] + breg[0];
        float fp = acc[1][rr] + breg[1];
        float gp = acc[2][rr] + breg[2];
        float op = acc[3][rr] + breg[3];
        float cc = sigf(fp)*creg[m][rr] + sigf(ip)*tanhf_fast(gp);
        float hh = sigf(op)*tanhf_fast(cc);
        creg[m][rr] = cc;
        const int row = m*16 + quad*4 + rr;
        hnxt[row][u] = (_Float16)hh;
        if (t == S_LEN-1){
          h_enc[((size_t)l*BATCH + r0 + row)*HID + u] = (_Float16)hh;
          c_enc[((size_t)l*BATCH + r0 + row)*HID + u] = cc;
        }
      }
    }
    __syncthreads();

    // ---- publish h (layers 0..2), then signal ----
    if (l < 3){
      int* dst = (int*)(ring + (((size_t)l*8 + (t&7))*BATCH + r0)*HID);
      #pragma unroll
      for (int jj = 0; jj < 4; ++jj){
        int d = tid + jj*512;
        int v = *(const int*)&hnxt[d>>6][(d&63)*2];
        stc(dst + d, v);
      }
    }
    drain_vm();
    __syncthreads();
    if (tid == 0) stc(flag_self, t+1);
    _Float16 (*tmp)[136] = hcur; hcur = hnxt; hnxt = tmp;
  }
}

__global__ __launch_bounds__(512, 2)
void dec_pipe(const float* __restrict__ x, const _Float16* __restrict__ decw,
              const float* __restrict__ dec_b, const float* __restrict__ fc_b,
              _Float16* __restrict__ ring, _Float16* __restrict__ oring,
              const _Float16* __restrict__ h_enc, const float* __restrict__ c_enc,
              int* __restrict__ flags, float* __restrict__ out)
{
  const int tid = threadIdx.x;
  const int w = tid >> 6, lane = tid & 63, quad = lane >> 4, n16 = lane & 15;
  const int l = blockIdx.x >> 6, s = blockIdx.x & 63, r0 = s * 32;
  const int u = w*16 + n16;
  const int KSI = (l == 0) ? 2 : 4;

  __shared__ _Float16 xbuf[32][136];
  __shared__ _Float16 hb[2][32][136];
  __shared__ _Float16 fcout[32][64];

  for (int i = tid; i < 32*136; i += 512) ((_Float16*)xbuf)[i] = (_Float16)0.f;
  // FIX (round-3 NaN): zero ALL of fcout. Waves 0..2 only ever write cols
  // 0..47; cols 48..63 were uninitialized LDS shipped to oring -> xbuf ->
  // MFMA A-operand, where f16 NaN/Inf garbage * 0-pad weight = NaN.
  for (int i = tid; i < 32*64; i += 512) ((_Float16*)fcout)[i] = (_Float16)0.f;

  const _Float16* Wi = (l==0) ? decw : decw + 32768 + (size_t)(l-1)*65536;
  const _Float16* Wh = decw + 229376 + (size_t)l*65536;
  const _Float16* FCW = decw + 491520;
  const int KI = KSI * 32;
  half8 wfi[4][4], wfh[4][4];
  #pragma unroll
  for (int nt = 0; nt < 4; ++nt){
    const int grow = nt*128 + u;
    #pragma unroll
    for (int ks = 0; ks < 4; ++ks){
      if (ks < KSI) wfi[nt][ks] = *(const half8*)(Wi + (size_t)grow*KI + ks*32 + quad*8);
      wfh[nt][ks] = *(const half8*)(Wh + (size_t)grow*HID + ks*32 + quad*8);
    }
  }
  float breg[4];
  #pragma unroll
  for (int g = 0; g < 4; ++g) breg[g] = dec_b[l*512 + g*128 + u];

  {
    int idx = tid*8, rr_ = idx >> 7, kk = idx & 127;
    *(half8*)&hb[0][rr_][kk] = *(const half8*)(h_enc + ((size_t)l*BATCH + r0)*HID + rr_*HID + kk);
  }
  float creg[2][4];
  #pragma unroll
  for (int m = 0; m < 2; ++m)
    #pragma unroll
    for (int rr = 0; rr < 4; ++rr)
      creg[m][rr] = c_enc[((size_t)l*BATCH + r0 + m*16 + quad*4 + rr)*HID + u];

  half8 wfc[4]; float fcb_j = 0.f;
  const int j = w*16 + n16;
  if (w < 3){
    #pragma unroll
    for (int ks = 0; ks < 4; ++ks)
      wfc[ks] = *(const half8*)(FCW + (size_t)j*HID + ks*32 + quad*8);
    if (j < IN_D) fcb_j = fc_b[j];
  }

  int* flag_self = flagp(flags, 256 + l*64 + s);
  int* flag_in   = flagp(flags, 256 + (l-1)*64 + s);  // l>0
  int* flag_fc   = flagp(flags, 256 + 3*64 + s);      // l==0 waits on layer 3

  __syncthreads();

  _Float16 (*hcur)[136] = hb[0];
  _Float16 (*hnxt)[136] = hb[1];

  for (int t = 0; t < T_LEN; ++t){
    if (tid == 0){
      if (l > 0)      while (ldc(flag_in) < t+1) __builtin_amdgcn_s_sleep(1);
      else if (t > 0) while (ldc(flag_fc) < t)   __builtin_amdgcn_s_sleep(1);
    }
    __syncthreads();

    // ---- stage input ----
    if (l == 0){
      if (t == 0){
        for (int idx = tid; idx < 32*IN_D; idx += 512){
          int r = idx / IN_D, k = idx % IN_D;
          xbuf[r][k] = (_Float16)x[((size_t)(r0+r)*S_LEN + (S_LEN-1))*IN_D + k];
        }
      } else {
        const int* src = (const int*)(oring + ((size_t)((t-1)&1)*BATCH + r0)*64);
        #pragma unroll
        for (int jj = 0; jj < 2; ++jj){
          int d = tid + jj*512;              // 1024 ints = 32 rows x 32
          int v = ldc(src + d);
          *(int*)&xbuf[d>>5][(d&31)*2] = v;
        }
      }
    } else {
      const int* src = (const int*)(ring + (((size_t)(l-1)*2 + (t&1))*BATCH + r0)*HID);
      #pragma unroll
      for (int jj = 0; jj < 4; ++jj){
        int d = tid + jj*512;
        int v = ldc(src + d);
        *(int*)&xbuf[d>>6][(d&63)*2] = v;
      }
    }
    __syncthreads();

    // ---- gates + cell update ----
    #pragma unroll
    for (int m = 0; m < 2; ++m){
      half8 ai[4], ah[4];
      #pragma unroll
      for (int ks = 0; ks < 4; ++ks){
        if (ks < KSI) ai[ks] = *(const half8*)&xbuf[m*16+n16][ks*32 + quad*8];
        ah[ks] = *(const half8*)&hcur[m*16+n16][ks*32 + quad*8];
      }
      floatx4 acc[4];
      #pragma unroll
      for (int nt = 0; nt < 4; ++nt){
        acc[nt] = (floatx4){0.f,0.f,0.f,0.f};
        #pragma unroll
        for (int ks = 0; ks < 4; ++ks){
          if (ks < KSI) acc[nt] = __builtin_amdgcn_mfma_f32_16x16x32_f16(ai[ks], wfi[nt][ks], acc[nt], 0,0,0);
          acc[nt] = __builtin_amdgcn_mfma_f32_16x16x32_f16(ah[ks], wfh[nt][ks], acc[nt], 0,0,0);
        }
      }
      #pragma unroll
      for (int rr = 0; rr < 4; ++rr){
        float ip = acc[0][rr] + breg[0];
        float fp = acc[1][rr] + breg[1];
        float gp = acc[2][rr] + breg[2];
        float op = acc[3][rr] + breg[3];
        float cc = sigf(fp)*creg[m][rr] + sigf(ip)*tanhf_fast(gp);
        float hh = sigf(op)*tanhf_fast(cc);
        creg[m][rr] = cc;
        hnxt[m*16 + quad*4 + rr][u] = (_Float16)hh;
      }
    }
    __syncthreads();

    if (l < 3){
      int* dst = (int*)(ring + (((size_t)l*2 + (t&1))*BATCH + r0)*HID);
      #pragma unroll
      for (int jj = 0; jj < 4; ++jj){
        int d = tid + jj*512;
        int v = *(const int*)&hnxt[d>>6][(d&63)*2];
        stc(dst + d, v);
      }
    } else {
      // ---- FC + output + feedback (waves 0..2 cover cols 0..47) ----
      if (w < 3){
        #pragma unroll
        for (int m = 0; m < 2; ++m){
          half8 a3[4];
          #pragma unroll
          for (int ks = 0; ks < 4; ++ks) a3[ks] = *(const half8*)&hnxt[m*16+n16][ks*32 + quad*8];
          floatx4 facc = (floatx4){0.f,0.f,0.f,0.f};
          #pragma unroll
          for (int ks = 0; ks < 4; ++ks) facc = __builtin_amdgcn_mfma_f32_16x16x32_f16(a3[ks], wfc[ks], facc, 0,0,0);
          #pragma unroll
          for (int rr = 0; rr < 4; ++rr){
            const int row = m*16 + quad*4 + rr;
            float v = facc[rr] + fcb_j;
            fcout[row][j] = (_Float16)v;          // cols 48..63 stay zero
            if (j < IN_D)
              out[((size_t)(r0 + row)*T_LEN + t)*IN_D + j] = v;
          }
        }
      }
      __syncthreads();
      int* odst = (int*)(oring + ((size_t)(t&1)*BATCH + r0)*64);
      #pragma unroll
      for (int jj = 0; jj < 2; ++jj){
        int d = tid + jj*512;
        int v = *(const int*)&fcout[d>>5][(d&31)*2];
        stc(odst + d, v);
      }
    }
    drain_vm();
    __syncthreads();
    if (tid == 0) stc(flag_self, t+1);
    _Float16 (*tmp)[136] = hcur; hcur = hnxt; hnxt = tmp;
  }
}

extern "C" void kernel_launch(void* const* d_in, const int* in_sizes, int n_in,
                              void* d_out, int out_size, void* d_ws, size_t ws_size,
                              hipStream_t stream)
{
  const float* x        = (const float*)d_in[0];
  const float* enc_Wih0 = (const float*)d_in[2];
  const float* enc_WihR = (const float*)d_in[3];
  const float* enc_Whh  = (const float*)d_in[4];
  const float* enc_b    = (const float*)d_in[5];
  const float* dec_Wih0 = (const float*)d_in[6];
  const float* dec_WihR = (const float*)d_in[7];
  const float* dec_Whh  = (const float*)d_in[8];
  const float* dec_b    = (const float*)d_in[9];
  const float* fc_W     = (const float*)d_in[10];
  const float* fc_b     = (const float*)d_in[11];

  char* ws = (char*)d_ws;
  _Float16* encw   = (_Float16*)(ws + OFF_ENCW);
  _Float16* decw   = (_Float16*)(ws + OFF_DECW);
  _Float16* ring_e = (_Float16*)(ws + OFF_RING_E);
  _Float16* ring_d = (_Float16*)(ws + OFF_RING_D);
  _Float16* oring  = (_Float16*)(ws + OFF_ORING);
  _Float16* h_enc  = (_Float16*)(ws + OFF_HENC);
  float*    c_enc  = (float*)(ws + OFF_CENC);
  int*      flags  = (int*)(ws + OFF_FLAGS);
  float*    outp   = (float*)d_out;

  prep_weights<<<1944, 256, 0, stream>>>(enc_Wih0, enc_WihR, enc_Whh,
                                         dec_Wih0, dec_WihR, dec_Whh, fc_W,
                                         encw, decw, oring, flags);
  enc_pipe<<<256, 512, 0, stream>>>(x, encw, enc_b, ring_e, h_enc, c_enc, flags);
  dec_pipe<<<256, 512, 0, stream>>>(x, decw, dec_b, fc_b, ring_d, oring,
                                    h_enc, c_enc, flags, outp);
}

// Round 5
// 1643.906 us; speedup vs baseline: 2.1031x; 1.3946x over previous
//
#include <hip/hip_runtime.h>
#include <hip/hip_bf16.h>
#include <cstdint>
#include <cstddef>

typedef _Float16 half8  __attribute__((ext_vector_type(8)));
typedef float    floatx4 __attribute__((ext_vector_type(4)));

#define S_LEN 200
#define BATCH 2048
#define HID   128
#define T_LEN 50
#define IN_D  44

// ---- workspace byte offsets ----
// encw/decw layout (f16 elems): W0 [512][64] @0 (K padded 44->64),
//   WR [3][512][128] @32768, WH [4][512][128] @229376, FCW [48][128] @491520 (dec only)
#define OFF_ENCW   0ull
#define OFF_DECW   983040ull
#define OFF_RING_E 1978368ull    // [3][8][2048][128] f16 = 12,582,912 B
#define OFF_RING_D 14561280ull   // [3][2][2048][128] f16 = 3,145,728 B
#define OFF_ORING  17707008ull   // [2][2048][64] f16 = 524,288 B
#define OFF_HENC   18231296ull   // [4][2048][128] f16 = 2,097,152 B
#define OFF_CENC   20328448ull   // [4][2048][128] f32 = 4,194,304 B
#define OFF_FLAGS  24522752ull   // int[512*32]: flag i at [i*32] (128B apart)

#define SCOPE_AGENT __HIP_MEMORY_SCOPE_AGENT

// Fast gate math: v_exp_f32 (exp2) + v_rcp_f32, no division sequences, no
// clamps (exp2 saturates: x->+inf => rcp(inf)=0 => tanh->1; x->-inf => -1).
#define LOG2E  1.44269504f
#define LOG2E2 2.88539008f
__device__ __forceinline__ float sigf(float x){
  float e = __builtin_amdgcn_exp2f(-LOG2E * x);
  return __builtin_amdgcn_rcpf(1.f + e);
}
__device__ __forceinline__ float tanhf_fast(float x){
  float e = __builtin_amdgcn_exp2f(LOG2E2 * x);
  return 1.f - 2.f * __builtin_amdgcn_rcpf(e + 1.f);
}

// Per-access coherent ops — no fences => no buffer_inv/buffer_wbl2 L2 nuking.
__device__ __forceinline__ int  ldc(const int* p){ return __hip_atomic_load(p, __ATOMIC_RELAXED, SCOPE_AGENT); }
__device__ __forceinline__ void stc(int* p, int v){ __hip_atomic_store(p, v, __ATOMIC_RELAXED, SCOPE_AGENT); }
__device__ __forceinline__ void drain_vm(){ asm volatile("s_waitcnt vmcnt(0)" ::: "memory"); }
__device__ __forceinline__ int* flagp(int* flags, int idx){ return flags + idx*32; }

// Force the compiler to materialize a fragment into VGPRs and keep it (defeats
// sinking the weight loads into the t-loop; VGPR_Count==128 in r4 says they
// were being re-fetched every stage).
#define PIN(v) asm volatile("" : "+v"(v))

__global__ void prep_weights(const float* __restrict__ eW0, const float* __restrict__ eWR,
                             const float* __restrict__ eWH, const float* __restrict__ dW0,
                             const float* __restrict__ dWR, const float* __restrict__ dWH,
                             const float* __restrict__ fcW,
                             _Float16* __restrict__ encw, _Float16* __restrict__ decw,
                             _Float16* __restrict__ oring, int* __restrict__ flags)
{
  int i = blockIdx.x*256 + threadIdx.x;
  if (i < 491520) {
    _Float16 v;
    if (i < 32768)      { int j=i>>6, k=i&63; v = (k<IN_D)? (_Float16)eW0[j*IN_D+k] : (_Float16)0.f; }
    else if (i < 229376){ v = (_Float16)eWR[i-32768]; }
    else                { v = (_Float16)eWH[i-229376]; }
    encw[i] = v;
  }
  if (i < 497664) {
    _Float16 v;
    if (i < 32768)      { int j=i>>6, k=i&63; v = (k<IN_D)? (_Float16)dW0[j*IN_D+k] : (_Float16)0.f; }
    else if (i < 229376){ v = (_Float16)dWR[i-32768]; }
    else if (i < 491520){ v = (_Float16)dWH[i-229376]; }
    else { int r=i-491520; int j=r>>7, k=r&127; v = (j<IN_D)? (_Float16)fcW[j*HID+k] : (_Float16)0.f; }
    decw[i] = v;
  }
  if (i < 262144) oring[i] = (_Float16)0.f;   // ws is 0xAA-poisoned each launch
  if (i < 16384)  flags[i] = 0;
}

// ============================================================================
// Persistent pipelined LSTM. Grid = 4 layers x 64 slices = 256 blocks, 512 thr,
// launch_bounds(512,2) => full grid co-resident => spin-waits deadlock-free.
// Wave w owns units u=w*16+n16; its 4 N-tiles are gates {i,f,g,o} of those
// units => cell update fully in registers. Weights pinned register-resident.
// Cross-block handoff: coherent dword ring I/O + padded flag + vmcnt drain.
// ============================================================================

__global__ __launch_bounds__(512, 2)
void enc_pipe(const float* __restrict__ x, const _Float16* __restrict__ encw,
              const float* __restrict__ enc_b, _Float16* __restrict__ ring,
              _Float16* __restrict__ h_enc, float* __restrict__ c_enc,
              int* __restrict__ flags)
{
  const int tid = threadIdx.x;
  const int w = tid >> 6, lane = tid & 63, quad = lane >> 4, n16 = lane & 15;
  const int l = blockIdx.x >> 6, s = blockIdx.x & 63, r0 = s * 32;
  const int u = w*16 + n16;
  const int KSI = (l == 0) ? 2 : 4;

  __shared__ _Float16 xbuf[32][136];
  __shared__ _Float16 hb[2][32][136];

  for (int i = tid; i < 32*136; i += 512){
    ((_Float16*)xbuf)[i] = (_Float16)0.f;
    ((_Float16*)hb[0])[i] = (_Float16)0.f;
  }

  const _Float16* Wi = (l==0) ? encw : encw + 32768 + (size_t)(l-1)*65536;
  const _Float16* Wh = encw + 229376 + (size_t)l*65536;
  const int KI = KSI * 32;
  floatx4 wfi[4][4], wfh[4][4];
  #pragma unroll
  for (int nt = 0; nt < 4; ++nt){
    const int grow = nt*128 + u;
    #pragma unroll
    for (int ks = 0; ks < 4; ++ks){
      if (ks < KSI){ wfi[nt][ks] = *(const floatx4*)(Wi + (size_t)grow*KI + ks*32 + quad*8); PIN(wfi[nt][ks]); }
      wfh[nt][ks] = *(const floatx4*)(Wh + (size_t)grow*HID + ks*32 + quad*8); PIN(wfh[nt][ks]);
    }
  }
  float breg[4];
  #pragma unroll
  for (int g = 0; g < 4; ++g) breg[g] = enc_b[l*512 + g*128 + u];
  float creg[2][4] = {{0.f,0.f,0.f,0.f},{0.f,0.f,0.f,0.f}};

  // layer-0 x prefetch (3 elems/thread covers 32*44=1408)
  int xr_r[3], xr_k[3]; bool xr_v[3]; float xr[3];
  if (l == 0){
    #pragma unroll
    for (int j = 0; j < 3; ++j){
      int idx = tid + j*512; xr_v[j] = idx < 32*IN_D;
      xr_r[j] = xr_v[j] ? idx / IN_D : 0; xr_k[j] = xr_v[j] ? idx % IN_D : 0;
      xr[j] = xr_v[j] ? x[((size_t)(r0+xr_r[j])*S_LEN + 0)*IN_D + xr_k[j]] : 0.f;
    }
  }

  int* flag_self = flagp(flags, l*64 + s);
  int* flag_in   = flagp(flags, (l-1)*64 + s);   // l>0
  int* flag_cons = flagp(flags, (l+1)*64 + s);   // l<3
  int seen_in = 0, seen_cons = 0;                // cached (tid0): skip poll when ahead

  __syncthreads();

  _Float16 (*hcur)[136] = hb[0];
  _Float16 (*hnxt)[136] = hb[1];

  for (int t = 0; t < S_LEN; ++t){
    if (tid == 0){
      if (l > 0){
        while (seen_in < t+1){
          seen_in = ldc(flag_in);
          if (seen_in < t+1) __builtin_amdgcn_s_sleep(1);
        }
      }
      if (l < 3 && t >= 8){
        while (seen_cons < t-7){
          seen_cons = ldc(flag_cons);
          if (seen_cons < t-7) __builtin_amdgcn_s_sleep(1);
        }
      }
    }
    __syncthreads();

    // ---- stage input ----
    if (l == 0){
      #pragma unroll
      for (int j = 0; j < 3; ++j)
        if (xr_v[j]) xbuf[xr_r[j]][xr_k[j]] = (_Float16)xr[j];
    } else {
      const int* src = (const int*)(ring + (((size_t)(l-1)*8 + (t&7))*BATCH + r0)*HID);
      #pragma unroll
      for (int jj = 0; jj < 4; ++jj){
        int d = tid + jj*512;                // 2048 ints = 32 rows x 64
        int v = ldc(src + d);
        *(int*)&xbuf[d>>6][(d&63)*2] = v;
      }
    }
    __syncthreads();

    if (l == 0 && t < S_LEN-1){
      #pragma unroll
      for (int j = 0; j < 3; ++j)
        if (xr_v[j]) xr[j] = x[((size_t)(r0+xr_r[j])*S_LEN + (t+1))*IN_D + xr_k[j]];
    }

    // ---- gates via MFMA + in-register cell update ----
    #pragma unroll
    for (int m = 0; m < 2; ++m){
      half8 ai[4], ah[4];
      #pragma unroll
      for (int ks = 0; ks < 4; ++ks){
        if (ks < KSI) ai[ks] = *(const half8*)&xbuf[m*16+n16][ks*32 + quad*8];
        ah[ks] = *(const half8*)&hcur[m*16+n16][ks*32 + quad*8];
      }
      floatx4 acc[4];
      #pragma unroll
      for (int nt = 0; nt < 4; ++nt){
        acc[nt] = (floatx4){0.f,0.f,0.f,0.f};
        #pragma unroll
        for (int ks = 0; ks < 4; ++ks){
          if (ks < KSI) acc[nt] = __builtin_amdgcn_mfma_f32_16x16x32_f16(ai[ks], __builtin_bit_cast(half8, wfi[nt][ks]), acc[nt], 0,0,0);
          acc[nt] = __builtin_amdgcn_mfma_f32_16x16x32_f16(ah[ks], __builtin_bit_cast(half8, wfh[nt][ks]), acc[nt], 0,0,0);
        }
      }
      #pragma unroll
      for (int rr = 0; rr < 4; ++rr){
        float ip = acc[0][rr] + breg[0];
        float fp = acc[1][rr] + breg[1];
        float gp = acc[2][rr] + breg[2];
        float op = acc[3][rr] + breg[3];
        float cc = sigf(fp)*creg[m][rr] + sigf(ip)*tanhf_fast(gp);
        float hh = sigf(op)*tanhf_fast(cc);
        creg[m][rr] = cc;
        const int row = m*16 + quad*4 + rr;
        hnxt[row][u] = (_Float16)hh;
        if (t == S_LEN-1){
          h_enc[((size_t)l*BATCH + r0 + row)*HID + u] = (_Float16)hh;
          c_enc[((size_t)l*BATCH + r0 + row)*HID + u] = cc;
        }
      }
    }
    __syncthreads();

    // ---- publish h (layers 0..2), then signal ----
    if (l < 3){
      int* dst = (int*)(ring + (((size_t)l*8 + (t&7))*BATCH + r0)*HID);
      #pragma unroll
      for (int jj = 0; jj < 4; ++jj){
        int d = tid + jj*512;
        int v = *(const int*)&hnxt[d>>6][(d&63)*2];
        stc(dst + d, v);
      }
    }
    drain_vm();
    __syncthreads();
    if (tid == 0) stc(flag_self, t+1);
    _Float16 (*tmp)[136] = hcur; hcur = hnxt; hnxt = tmp;
  }
}

__global__ __launch_bounds__(512, 2)
void dec_pipe(const float* __restrict__ x, const _Float16* __restrict__ decw,
              const float* __restrict__ dec_b, const float* __restrict__ fc_b,
              _Float16* __restrict__ ring, _Float16* __restrict__ oring,
              const _Float16* __restrict__ h_enc, const float* __restrict__ c_enc,
              int* __restrict__ flags, float* __restrict__ out)
{
  const int tid = threadIdx.x;
  const int w = tid >> 6, lane = tid & 63, quad = lane >> 4, n16 = lane & 15;
  const int l = blockIdx.x >> 6, s = blockIdx.x & 63, r0 = s * 32;
  const int u = w*16 + n16;
  const int KSI = (l == 0) ? 2 : 4;

  __shared__ _Float16 xbuf[32][136];
  __shared__ _Float16 hb[2][32][136];
  __shared__ _Float16 fcout[32][64];

  for (int i = tid; i < 32*136; i += 512) ((_Float16*)xbuf)[i] = (_Float16)0.f;
  // cols 48..63 of fcout must be zero forever (only cols 0..47 get written)
  for (int i = tid; i < 32*64; i += 512) ((_Float16*)fcout)[i] = (_Float16)0.f;

  const _Float16* Wi = (l==0) ? decw : decw + 32768 + (size_t)(l-1)*65536;
  const _Float16* Wh = decw + 229376 + (size_t)l*65536;
  const _Float16* FCW = decw + 491520;
  const int KI = KSI * 32;
  floatx4 wfi[4][4], wfh[4][4];
  #pragma unroll
  for (int nt = 0; nt < 4; ++nt){
    const int grow = nt*128 + u;
    #pragma unroll
    for (int ks = 0; ks < 4; ++ks){
      if (ks < KSI){ wfi[nt][ks] = *(const floatx4*)(Wi + (size_t)grow*KI + ks*32 + quad*8); PIN(wfi[nt][ks]); }
      wfh[nt][ks] = *(const floatx4*)(Wh + (size_t)grow*HID + ks*32 + quad*8); PIN(wfh[nt][ks]);
    }
  }
  float breg[4];
  #pragma unroll
  for (int g = 0; g < 4; ++g) breg[g] = dec_b[l*512 + g*128 + u];

  {
    int idx = tid*8, rr_ = idx >> 7, kk = idx & 127;
    *(half8*)&hb[0][rr_][kk] = *(const half8*)(h_enc + ((size_t)l*BATCH + r0)*HID + rr_*HID + kk);
  }
  float creg[2][4];
  #pragma unroll
  for (int m = 0; m < 2; ++m)
    #pragma unroll
    for (int rr = 0; rr < 4; ++rr)
      creg[m][rr] = c_enc[((size_t)l*BATCH + r0 + m*16 + quad*4 + rr)*HID + u];

  floatx4 wfc[4]; float fcb_j = 0.f;
  const int j = w*16 + n16;
  if (w < 3){
    #pragma unroll
    for (int ks = 0; ks < 4; ++ks){
      wfc[ks] = *(const floatx4*)(FCW + (size_t)j*HID + ks*32 + quad*8); PIN(wfc[ks]);
    }
    if (j < IN_D) fcb_j = fc_b[j];
  }

  int* flag_self = flagp(flags, 256 + l*64 + s);
  int* flag_in   = flagp(flags, 256 + (l-1)*64 + s);  // l>0
  int* flag_fc   = flagp(flags, 256 + 3*64 + s);      // l==0 waits on layer 3
  int seen = 0;

  __syncthreads();

  _Float16 (*hcur)[136] = hb[0];
  _Float16 (*hnxt)[136] = hb[1];

  for (int t = 0; t < T_LEN; ++t){
    if (tid == 0){
      if (l > 0){
        while (seen < t+1){ seen = ldc(flag_in); if (seen < t+1) __builtin_amdgcn_s_sleep(1); }
      } else if (t > 0){
        while (seen < t){ seen = ldc(flag_fc); if (seen < t) __builtin_amdgcn_s_sleep(1); }
      }
    }
    __syncthreads();

    // ---- stage input ----
    if (l == 0){
      if (t == 0){
        for (int idx = tid; idx < 32*IN_D; idx += 512){
          int r = idx / IN_D, k = idx % IN_D;
          xbuf[r][k] = (_Float16)x[((size_t)(r0+r)*S_LEN + (S_LEN-1))*IN_D + k];
        }
      } else {
        const int* src = (const int*)(oring + ((size_t)((t-1)&1)*BATCH + r0)*64);
        #pragma unroll
        for (int jj = 0; jj < 2; ++jj){
          int d = tid + jj*512;              // 1024 ints = 32 rows x 32
          int v = ldc(src + d);
          *(int*)&xbuf[d>>5][(d&31)*2] = v;
        }
      }
    } else {
      const int* src = (const int*)(ring + (((size_t)(l-1)*2 + (t&1))*BATCH + r0)*HID);
      #pragma unroll
      for (int jj = 0; jj < 4; ++jj){
        int d = tid + jj*512;
        int v = ldc(src + d);
        *(int*)&xbuf[d>>6][(d&63)*2] = v;
      }
    }
    __syncthreads();

    // ---- gates + cell update ----
    #pragma unroll
    for (int m = 0; m < 2; ++m){
      half8 ai[4], ah[4];
      #pragma unroll
      for (int ks = 0; ks < 4; ++ks){
        if (ks < KSI) ai[ks] = *(const half8*)&xbuf[m*16+n16][ks*32 + quad*8];
        ah[ks] = *(const half8*)&hcur[m*16+n16][ks*32 + quad*8];
      }
      floatx4 acc[4];
      #pragma unroll
      for (int nt = 0; nt < 4; ++nt){
        acc[nt] = (floatx4){0.f,0.f,0.f,0.f};
        #pragma unroll
        for (int ks = 0; ks < 4; ++ks){
          if (ks < KSI) acc[nt] = __builtin_amdgcn_mfma_f32_16x16x32_f16(ai[ks], __builtin_bit_cast(half8, wfi[nt][ks]), acc[nt], 0,0,0);
          acc[nt] = __builtin_amdgcn_mfma_f32_16x16x32_f16(ah[ks], __builtin_bit_cast(half8, wfh[nt][ks]), acc[nt], 0,0,0);
        }
      }
      #pragma unroll
      for (int rr = 0; rr < 4; ++rr){
        float ip = acc[0][rr] + breg[0];
        float fp = acc[1][rr] + breg[1];
        float gp = acc[2][rr] + breg[2];
        float op = acc[3][rr] + breg[3];
        float cc = sigf(fp)*creg[m][rr] + sigf(ip)*tanhf_fast(gp);
        float hh = sigf(op)*tanhf_fast(cc);
        creg[m][rr] = cc;
        hnxt[m*16 + quad*4 + rr][u] = (_Float16)hh;
      }
    }
    __syncthreads();

    if (l < 3){
      int* dst = (int*)(ring + (((size_t)l*2 + (t&1))*BATCH + r0)*HID);
      #pragma unroll
      for (int jj = 0; jj < 4; ++jj){
        int d = tid + jj*512;
        int v = *(const int*)&hnxt[d>>6][(d&63)*2];
        stc(dst + d, v);
      }
    } else {
      // ---- FC + output + feedback (waves 0..2 cover cols 0..47) ----
      if (w < 3){
        #pragma unroll
        for (int m = 0; m < 2; ++m){
          half8 a3[4];
          #pragma unroll
          for (int ks = 0; ks < 4; ++ks) a3[ks] = *(const half8*)&hnxt[m*16+n16][ks*32 + quad*8];
          floatx4 facc = (floatx4){0.f,0.f,0.f,0.f};
          #pragma unroll
          for (int ks = 0; ks < 4; ++ks) facc = __builtin_amdgcn_mfma_f32_16x16x32_f16(a3[ks], __builtin_bit_cast(half8, wfc[ks]), facc, 0,0,0);
          #pragma unroll
          for (int rr = 0; rr < 4; ++rr){
            const int row = m*16 + quad*4 + rr;
            float v = facc[rr] + fcb_j;
            fcout[row][j] = (_Float16)v;          // cols 48..63 stay zero
            if (j < IN_D)
              out[((size_t)(r0 + row)*T_LEN + t)*IN_D + j] = v;
          }
        }
      }
      __syncthreads();
      int* odst = (int*)(oring + ((size_t)(t&1)*BATCH + r0)*64);
      #pragma unroll
      for (int jj = 0; jj < 2; ++jj){
        int d = tid + jj*512;
        int v = *(const int*)&fcout[d>>5][(d&31)*2];
        stc(odst + d, v);
      }
    }
    drain_vm();
    __syncthreads();
    if (tid == 0) stc(flag_self, t+1);
    _Float16 (*tmp)[136] = hcur; hcur = hnxt; hnxt = tmp;
  }
}

extern "C" void kernel_launch(void* const* d_in, const int* in_sizes, int n_in,
                              void* d_out, int out_size, void* d_ws, size_t ws_size,
                              hipStream_t stream)
{
  const float* x        = (const float*)d_in[0];
  const float* enc_Wih0 = (const float*)d_in[2];
  const float* enc_WihR = (const float*)d_in[3];
  const float* enc_Whh  = (const float*)d_in[4];
  const float* enc_b    = (const float*)d_in[5];
  const float* dec_Wih0 = (const float*)d_in[6];
  const float* dec_WihR = (const float*)d_in[7];
  const float* dec_Whh  = (const float*)d_in[8];
  const float* dec_b    = (const float*)d_in[9];
  const float* fc_W     = (const float*)d_in[10];
  const float* fc_b     = (const float*)d_in[11];

  char* ws = (char*)d_ws;
  _Float16* encw   = (_Float16*)(ws + OFF_ENCW);
  _Float16* decw   = (_Float16*)(ws + OFF_DECW);
  _Float16* ring_e = (_Float16*)(ws + OFF_RING_E);
  _Float16* ring_d = (_Float16*)(ws + OFF_RING_D);
  _Float16* oring  = (_Float16*)(ws + OFF_ORING);
  _Float16* h_enc  = (_Float16*)(ws + OFF_HENC);
  float*    c_enc  = (float*)(ws + OFF_CENC);
  int*      flags  = (int*)(ws + OFF_FLAGS);
  float*    outp   = (float*)d_out;

  prep_weights<<<1944, 256, 0, stream>>>(enc_Wih0, enc_WihR, enc_Whh,
                                         dec_Wih0, dec_WihR, dec_Whh, fc_W,
                                         encw, decw, oring, flags);
  enc_pipe<<<256, 512, 0, stream>>>(x, encw, enc_b, ring_e, h_enc, c_enc, flags);
  dec_pipe<<<256, 512, 0, stream>>>(x, decw, dec_b, fc_b, ring_d, oring,
                                    h_enc, c_enc, flags, outp);
}

// Round 6
// 1452.101 us; speedup vs baseline: 2.3809x; 1.1321x over previous
//
#include <hip/hip_runtime.h>
#include <hip/hip_bf16.h>
#include <cstdint>
#include <cstddef>

typedef _Float16 half8  __attribute__((ext_vector_type(8)));
typedef float    floatx4 __attribute__((ext_vector_type(4)));

#define S_LEN 200
#define BATCH 2048
#define HID   128
#define T_LEN 50
#define IN_D  44

// Sentinel: two f16 NaNs. h/FC values are finite => data dword never equals it.
#define SENT32 0x7E007E00

// ---- workspace byte offsets ----
// encw/decw layout (f16 elems): W0 [512][64] @0 (K padded 44->64),
//   WR [3][512][128] @32768, WH [4][512][128] @229376, FCW [48][128] @491520 (dec only)
#define OFF_ENCW   0ull
#define OFF_DECW   983040ull
#define OFF_RING_E 1978368ull    // [3][8][2048][128] f16 = 12,582,912 B
#define OFF_RING_D 14561280ull   // [3][4][2048][128] f16 = 6,291,456 B
#define OFF_ORING  20852736ull   // [4][2048][64] f16 = 1,048,576 B
#define OFF_HENC   21901312ull   // [4][2048][128] f16 = 2,097,152 B
#define OFF_CENC   23998464ull   // [4][2048][128] f32 = 4,194,304 B
#define OFF_FLAGS  28192768ull   // int[1024*32]: flag i at [i*32] (128B apart)
// rings (RING_E..ORING) are contiguous: 19,922,944 B = 4,980,736 dwords

#define SCOPE_AGENT __HIP_MEMORY_SCOPE_AGENT

#define LOG2E  1.44269504f
#define LOG2E2 2.88539008f
__device__ __forceinline__ float sigf(float x){
  float e = __builtin_amdgcn_exp2f(-LOG2E * x);
  return __builtin_amdgcn_rcpf(1.f + e);
}
__device__ __forceinline__ float tanhf_fast(float x){
  float e = __builtin_amdgcn_exp2f(LOG2E2 * x);
  return 1.f - 2.f * __builtin_amdgcn_rcpf(e + 1.f);
}

__device__ __forceinline__ int  ldc(const int* p){ return __hip_atomic_load(p, __ATOMIC_RELAXED, SCOPE_AGENT); }
__device__ __forceinline__ void stc(int* p, int v){ __hip_atomic_store(p, v, __ATOMIC_RELAXED, SCOPE_AGENT); }
__device__ __forceinline__ void drain_vm(){ asm volatile("s_waitcnt vmcnt(0)" ::: "memory"); }
__device__ __forceinline__ int* flagp(int* flags, int idx){ return flags + idx*32; }

#define PIN(v) asm volatile("" : "+v"(v))

__global__ void prep_weights(const float* __restrict__ eW0, const float* __restrict__ eWR,
                             const float* __restrict__ eWH, const float* __restrict__ dW0,
                             const float* __restrict__ dWR, const float* __restrict__ dWH,
                             const float* __restrict__ fcW,
                             _Float16* __restrict__ encw, _Float16* __restrict__ decw,
                             int* __restrict__ rings, int* __restrict__ flags)
{
  int i = blockIdx.x*256 + threadIdx.x;
  if (i < 491520) {
    _Float16 v;
    if (i < 32768)      { int j=i>>6, k=i&63; v = (k<IN_D)? (_Float16)eW0[j*IN_D+k] : (_Float16)0.f; }
    else if (i < 229376){ v = (_Float16)eWR[i-32768]; }
    else                { v = (_Float16)eWH[i-229376]; }
    encw[i] = v;
  }
  if (i < 497664) {
    _Float16 v;
    if (i < 32768)      { int j=i>>6, k=i&63; v = (k<IN_D)? (_Float16)dW0[j*IN_D+k] : (_Float16)0.f; }
    else if (i < 229376){ v = (_Float16)dWR[i-32768]; }
    else if (i < 491520){ v = (_Float16)dWH[i-229376]; }
    else { int r=i-491520; int j=r>>7, k=r&127; v = (j<IN_D)? (_Float16)fcW[j*HID+k] : (_Float16)0.f; }
    decw[i] = v;
  }
  for (int j = i; j < 4980736; j += 4096*256) rings[j] = SENT32;  // sentinel-fill all rings
  if (i < 32768) flags[i] = 0;
}

// ============================================================================
// Persistent pipelined LSTM, data-as-flag handoff. Grid = 4 layers x 64
// slices = 256 blocks, 512 thr, launch_bounds(512,2) => all co-resident.
// Ring payload doubles as readiness flag (sentinel = f16 NaN pair; consumers
// poll their own dwords, write sentinel back after consuming). No producer
// drain / flag on the critical path; flags only for ring backpressure.
// ============================================================================

__global__ __launch_bounds__(512, 2)
void enc_pipe(const float* __restrict__ x, const _Float16* __restrict__ encw,
              const float* __restrict__ enc_b, _Float16* __restrict__ ring,
              _Float16* __restrict__ h_enc, float* __restrict__ c_enc,
              int* __restrict__ flags)
{
  const int tid = threadIdx.x;
  const int w = tid >> 6, lane = tid & 63, quad = lane >> 4, n16 = lane & 15;
  const int l = blockIdx.x >> 6, s = blockIdx.x & 63, r0 = s * 32;
  const int u = w*16 + n16;
  const int KSI = (l == 0) ? 2 : 4;

  __shared__ _Float16 xbuf[32][136];
  __shared__ _Float16 hb[2][32][136];

  for (int i = tid; i < 32*136; i += 512){
    ((_Float16*)xbuf)[i] = (_Float16)0.f;
    ((_Float16*)hb[0])[i] = (_Float16)0.f;
  }

  const _Float16* Wi = (l==0) ? encw : encw + 32768 + (size_t)(l-1)*65536;
  const _Float16* Wh = encw + 229376 + (size_t)l*65536;
  const int KI = KSI * 32;
  floatx4 wfi[4][4], wfh[4][4];
  #pragma unroll
  for (int nt = 0; nt < 4; ++nt){
    const int grow = nt*128 + u;
    #pragma unroll
    for (int ks = 0; ks < 4; ++ks){
      if (ks < KSI){ wfi[nt][ks] = *(const floatx4*)(Wi + (size_t)grow*KI + ks*32 + quad*8); PIN(wfi[nt][ks]); }
      wfh[nt][ks] = *(const floatx4*)(Wh + (size_t)grow*HID + ks*32 + quad*8); PIN(wfh[nt][ks]);
    }
  }
  float breg[4];
  #pragma unroll
  for (int g = 0; g < 4; ++g) breg[g] = enc_b[l*512 + g*128 + u];
  float creg[2][4] = {{0.f,0.f,0.f,0.f},{0.f,0.f,0.f,0.f}};

  // layer-0 x prefetch (3 elems/thread covers 32*44=1408)
  int xr_r[3], xr_k[3]; bool xr_v[3]; float xr[3];
  if (l == 0){
    #pragma unroll
    for (int j = 0; j < 3; ++j){
      int idx = tid + j*512; xr_v[j] = idx < 32*IN_D;
      xr_r[j] = xr_v[j] ? idx / IN_D : 0; xr_k[j] = xr_v[j] ? idx % IN_D : 0;
      xr[j] = xr_v[j] ? x[((size_t)(r0+xr_r[j])*S_LEN + 0)*IN_D + xr_k[j]] : 0.f;
    }
  }

  int* cflag_self = flagp(flags, l*64 + s);        // published by l>=1
  int* cflag_next = flagp(flags, (l+1)*64 + s);    // read by l<3 (backpressure)
  int seen_cons = 0;

  __syncthreads();

  _Float16 (*hcur)[136] = hb[0];
  _Float16 (*hnxt)[136] = hb[1];

  const int d0 = tid, d1 = tid+512, d2 = tid+1024, d3 = tid+1536;

  for (int t = 0; t < S_LEN; ++t){
    // ---- stage input (data-as-flag poll for l>0) ----
    if (l == 0){
      #pragma unroll
      for (int j = 0; j < 3; ++j)
        if (xr_v[j]) xbuf[xr_r[j]][xr_k[j]] = (_Float16)xr[j];
    } else {
      int* srcd = (int*)(ring + (((size_t)(l-1)*8 + (t&7))*BATCH + r0)*HID);
      int v0 = ldc(srcd+d0), v1 = ldc(srcd+d1), v2 = ldc(srcd+d2), v3 = ldc(srcd+d3);
      while (v0==SENT32 || v1==SENT32 || v2==SENT32 || v3==SENT32){
        if (v0==SENT32) v0 = ldc(srcd+d0);
        if (v1==SENT32) v1 = ldc(srcd+d1);
        if (v2==SENT32) v2 = ldc(srcd+d2);
        if (v3==SENT32) v3 = ldc(srcd+d3);
      }
      *(int*)&xbuf[d0>>6][(d0&63)*2] = v0;
      *(int*)&xbuf[d1>>6][(d1&63)*2] = v1;
      *(int*)&xbuf[d2>>6][(d2&63)*2] = v2;
      *(int*)&xbuf[d3>>6][(d3&63)*2] = v3;
      stc(srcd+d0, SENT32); stc(srcd+d1, SENT32);
      stc(srcd+d2, SENT32); stc(srcd+d3, SENT32);
    }
    // backpressure (slow path; depth-8 ring => nearly always cached-skip)
    if (tid == 0 && l < 3 && t >= 8){
      while (seen_cons < t-7){
        seen_cons = ldc(cflag_next);
        if (seen_cons < t-7) __builtin_amdgcn_s_sleep(1);
      }
    }
    __syncthreads();

    if (l == 0 && t < S_LEN-1){
      #pragma unroll
      for (int j = 0; j < 3; ++j)
        if (xr_v[j]) xr[j] = x[((size_t)(r0+xr_r[j])*S_LEN + (t+1))*IN_D + xr_k[j]];
    }

    // ---- gates via MFMA + in-register cell update ----
    #pragma unroll
    for (int m = 0; m < 2; ++m){
      half8 ai[4], ah[4];
      #pragma unroll
      for (int ks = 0; ks < 4; ++ks){
        if (ks < KSI) ai[ks] = *(const half8*)&xbuf[m*16+n16][ks*32 + quad*8];
        ah[ks] = *(const half8*)&hcur[m*16+n16][ks*32 + quad*8];
      }
      floatx4 acc[4];
      #pragma unroll
      for (int nt = 0; nt < 4; ++nt){
        acc[nt] = (floatx4){0.f,0.f,0.f,0.f};
        #pragma unroll
        for (int ks = 0; ks < 4; ++ks){
          if (ks < KSI) acc[nt] = __builtin_amdgcn_mfma_f32_16x16x32_f16(ai[ks], __builtin_bit_cast(half8, wfi[nt][ks]), acc[nt], 0,0,0);
          acc[nt] = __builtin_amdgcn_mfma_f32_16x16x32_f16(ah[ks], __builtin_bit_cast(half8, wfh[nt][ks]), acc[nt], 0,0,0);
        }
      }
      #pragma unroll
      for (int rr = 0; rr < 4; ++rr){
        float ip = acc[0][rr] + breg[0];
        float fp = acc[1][rr] + breg[1];
        float gp = acc[2][rr] + breg[2];
        float op = acc[3][rr] + breg[3];
        float cc = sigf(fp)*creg[m][rr] + sigf(ip)*tanhf_fast(gp);
        float hh = sigf(op)*tanhf_fast(cc);
        creg[m][rr] = cc;
        const int row = m*16 + quad*4 + rr;
        hnxt[row][u] = (_Float16)hh;
        if (t == S_LEN-1){
          h_enc[((size_t)l*BATCH + r0 + row)*HID + u] = (_Float16)hh;
          c_enc[((size_t)l*BATCH + r0 + row)*HID + u] = cc;
        }
      }
    }
    __syncthreads();

    // consumed-flag publish (sentinel-resets had the whole compute to land)
    if (l > 0){
      drain_vm();
      if (tid == 0) stc(cflag_self, t+1);
    }
    // ---- publish h: data IS the flag; no drain needed ----
    if (l < 3){
      int* dst = (int*)(ring + (((size_t)l*8 + (t&7))*BATCH + r0)*HID);
      stc(dst+d0, *(const int*)&hnxt[d0>>6][(d0&63)*2]);
      stc(dst+d1, *(const int*)&hnxt[d1>>6][(d1&63)*2]);
      stc(dst+d2, *(const int*)&hnxt[d2>>6][(d2&63)*2]);
      stc(dst+d3, *(const int*)&hnxt[d3>>6][(d3&63)*2]);
    }
    _Float16 (*tmp)[136] = hcur; hcur = hnxt; hnxt = tmp;
  }
}

__global__ __launch_bounds__(512, 2)
void dec_pipe(const float* __restrict__ x, const _Float16* __restrict__ decw,
              const float* __restrict__ dec_b, const float* __restrict__ fc_b,
              _Float16* __restrict__ ring, _Float16* __restrict__ oring,
              const _Float16* __restrict__ h_enc, const float* __restrict__ c_enc,
              int* __restrict__ flags, float* __restrict__ out)
{
  const int tid = threadIdx.x;
  const int w = tid >> 6, lane = tid & 63, quad = lane >> 4, n16 = lane & 15;
  const int l = blockIdx.x >> 6, s = blockIdx.x & 63, r0 = s * 32;
  const int u = w*16 + n16;
  const int KSI = (l == 0) ? 2 : 4;

  __shared__ _Float16 xbuf[32][136];
  __shared__ _Float16 hb[2][32][136];
  __shared__ _Float16 fcout[32][64];

  for (int i = tid; i < 32*136; i += 512) ((_Float16*)xbuf)[i] = (_Float16)0.f;
  for (int i = tid; i < 32*64; i += 512) ((_Float16*)fcout)[i] = (_Float16)0.f;

  const _Float16* Wi = (l==0) ? decw : decw + 32768 + (size_t)(l-1)*65536;
  const _Float16* Wh = decw + 229376 + (size_t)l*65536;
  const _Float16* FCW = decw + 491520;
  const int KI = KSI * 32;
  floatx4 wfi[4][4], wfh[4][4];
  #pragma unroll
  for (int nt = 0; nt < 4; ++nt){
    const int grow = nt*128 + u;
    #pragma unroll
    for (int ks = 0; ks < 4; ++ks){
      if (ks < KSI){ wfi[nt][ks] = *(const floatx4*)(Wi + (size_t)grow*KI + ks*32 + quad*8); PIN(wfi[nt][ks]); }
      wfh[nt][ks] = *(const floatx4*)(Wh + (size_t)grow*HID + ks*32 + quad*8); PIN(wfh[nt][ks]);
    }
  }
  float breg[4];
  #pragma unroll
  for (int g = 0; g < 4; ++g) breg[g] = dec_b[l*512 + g*128 + u];

  {
    int idx = tid*8, rr_ = idx >> 7, kk = idx & 127;
    *(half8*)&hb[0][rr_][kk] = *(const half8*)(h_enc + ((size_t)l*BATCH + r0)*HID + rr_*HID + kk);
  }
  float creg[2][4];
  #pragma unroll
  for (int m = 0; m < 2; ++m)
    #pragma unroll
    for (int rr = 0; rr < 4; ++rr)
      creg[m][rr] = c_enc[((size_t)l*BATCH + r0 + m*16 + quad*4 + rr)*HID + u];

  floatx4 wfc[4]; float fcb_j = 0.f;
  const int j = w*16 + n16;
  if (w < 3){
    #pragma unroll
    for (int ks = 0; ks < 4; ++ks){
      wfc[ks] = *(const floatx4*)(FCW + (size_t)j*HID + ks*32 + quad*8); PIN(wfc[ks]);
    }
    if (j < IN_D) fcb_j = fc_b[j];
  }

  int* cflag_self = flagp(flags, 256 + l*64 + s);   // published by l>=1 (ring_d)
  int* cflag_next = flagp(flags, 256 + (l+1)*64 + s); // read by l<3
  int* cflag_o    = flagp(flags, 512 + s);          // published by l0, read by l3
  int seen = 0;

  __syncthreads();

  _Float16 (*hcur)[136] = hb[0];
  _Float16 (*hnxt)[136] = hb[1];

  const int d0 = tid, d1 = tid+512, d2 = tid+1024, d3 = tid+1536;

  for (int t = 0; t < T_LEN; ++t){
    // ---- stage input ----
    if (l == 0){
      if (t == 0){
        for (int idx = tid; idx < 32*IN_D; idx += 512){
          int r = idx / IN_D, k = idx % IN_D;
          xbuf[r][k] = (_Float16)x[((size_t)(r0+r)*S_LEN + (S_LEN-1))*IN_D + k];
        }
      } else {
        int* srcd = (int*)(oring + (((size_t)((t-1)&3))*BATCH + r0)*64);
        int v0 = ldc(srcd+d0), v1 = ldc(srcd+d1);
        while (v0==SENT32 || v1==SENT32){
          if (v0==SENT32) v0 = ldc(srcd+d0);
          if (v1==SENT32) v1 = ldc(srcd+d1);
        }
        *(int*)&xbuf[d0>>5][(d0&31)*2] = v0;
        *(int*)&xbuf[d1>>5][(d1&31)*2] = v1;
        stc(srcd+d0, SENT32); stc(srcd+d1, SENT32);
      }
    } else {
      int* srcd = (int*)(ring + (((size_t)(l-1)*4 + (t&3))*BATCH + r0)*HID);
      int v0 = ldc(srcd+d0), v1 = ldc(srcd+d1), v2 = ldc(srcd+d2), v3 = ldc(srcd+d3);
      while (v0==SENT32 || v1==SENT32 || v2==SENT32 || v3==SENT32){
        if (v0==SENT32) v0 = ldc(srcd+d0);
        if (v1==SENT32) v1 = ldc(srcd+d1);
        if (v2==SENT32) v2 = ldc(srcd+d2);
        if (v3==SENT32) v3 = ldc(srcd+d3);
      }
      *(int*)&xbuf[d0>>6][(d0&63)*2] = v0;
      *(int*)&xbuf[d1>>6][(d1&63)*2] = v1;
      *(int*)&xbuf[d2>>6][(d2&63)*2] = v2;
      *(int*)&xbuf[d3>>6][(d3&63)*2] = v3;
      stc(srcd+d0, SENT32); stc(srcd+d1, SENT32);
      stc(srcd+d2, SENT32); stc(srcd+d3, SENT32);
    }
    // backpressure (slow path)
    if (tid == 0 && t >= 4){
      if (l < 3){
        while (seen < t-3){ seen = ldc(cflag_next); if (seen < t-3) __builtin_amdgcn_s_sleep(1); }
      } else {
        while (seen < t-2){ seen = ldc(cflag_o); if (seen < t-2) __builtin_amdgcn_s_sleep(1); }
      }
    }
    __syncthreads();

    // ---- gates + cell update ----
    #pragma unroll
    for (int m = 0; m < 2; ++m){
      half8 ai[4], ah[4];
      #pragma unroll
      for (int ks = 0; ks < 4; ++ks){
        if (ks < KSI) ai[ks] = *(const half8*)&xbuf[m*16+n16][ks*32 + quad*8];
        ah[ks] = *(const half8*)&hcur[m*16+n16][ks*32 + quad*8];
      }
      floatx4 acc[4];
      #pragma unroll
      for (int nt = 0; nt < 4; ++nt){
        acc[nt] = (floatx4){0.f,0.f,0.f,0.f};
        #pragma unroll
        for (int ks = 0; ks < 4; ++ks){
          if (ks < KSI) acc[nt] = __builtin_amdgcn_mfma_f32_16x16x32_f16(ai[ks], __builtin_bit_cast(half8, wfi[nt][ks]), acc[nt], 0,0,0);
          acc[nt] = __builtin_amdgcn_mfma_f32_16x16x32_f16(ah[ks], __builtin_bit_cast(half8, wfh[nt][ks]), acc[nt], 0,0,0);
        }
      }
      #pragma unroll
      for (int rr = 0; rr < 4; ++rr){
        float ip = acc[0][rr] + breg[0];
        float fp = acc[1][rr] + breg[1];
        float gp = acc[2][rr] + breg[2];
        float op = acc[3][rr] + breg[3];
        float cc = sigf(fp)*creg[m][rr] + sigf(ip)*tanhf_fast(gp);
        float hh = sigf(op)*tanhf_fast(cc);
        creg[m][rr] = cc;
        hnxt[m*16 + quad*4 + rr][u] = (_Float16)hh;
      }
    }
    __syncthreads();

    // consumed-flag publish
    drain_vm();
    if (tid == 0){
      if (l > 0) stc(cflag_self, t+1);
      else if (t > 0) stc(cflag_o, t+1);
    }

    if (l < 3){
      int* dst = (int*)(ring + (((size_t)l*4 + (t&3))*BATCH + r0)*HID);
      stc(dst+d0, *(const int*)&hnxt[d0>>6][(d0&63)*2]);
      stc(dst+d1, *(const int*)&hnxt[d1>>6][(d1&63)*2]);
      stc(dst+d2, *(const int*)&hnxt[d2>>6][(d2&63)*2]);
      stc(dst+d3, *(const int*)&hnxt[d3>>6][(d3&63)*2]);
    } else {
      // ---- FC + output + feedback (waves 0..2 cover cols 0..47) ----
      if (w < 3){
        #pragma unroll
        for (int m = 0; m < 2; ++m){
          half8 a3[4];
          #pragma unroll
          for (int ks = 0; ks < 4; ++ks) a3[ks] = *(const half8*)&hnxt[m*16+n16][ks*32 + quad*8];
          floatx4 facc = (floatx4){0.f,0.f,0.f,0.f};
          #pragma unroll
          for (int ks = 0; ks < 4; ++ks) facc = __builtin_amdgcn_mfma_f32_16x16x32_f16(a3[ks], __builtin_bit_cast(half8, wfc[ks]), facc, 0,0,0);
          #pragma unroll
          for (int rr = 0; rr < 4; ++rr){
            const int row = m*16 + quad*4 + rr;
            float v = facc[rr] + fcb_j;
            fcout[row][j] = (_Float16)v;          // cols 48..63 stay zero
            if (j < IN_D)
              out[((size_t)(r0 + row)*T_LEN + t)*IN_D + j] = v;
          }
        }
      }
      __syncthreads();
      int* odst = (int*)(oring + (((size_t)(t&3))*BATCH + r0)*64);
      stc(odst+d0, *(const int*)&fcout[d0>>5][(d0&31)*2]);
      stc(odst+d1, *(const int*)&fcout[d1>>5][(d1&31)*2]);
    }
    _Float16 (*tmp)[136] = hcur; hcur = hnxt; hnxt = tmp;
  }
}

extern "C" void kernel_launch(void* const* d_in, const int* in_sizes, int n_in,
                              void* d_out, int out_size, void* d_ws, size_t ws_size,
                              hipStream_t stream)
{
  const float* x        = (const float*)d_in[0];
  const float* enc_Wih0 = (const float*)d_in[2];
  const float* enc_WihR = (const float*)d_in[3];
  const float* enc_Whh  = (const float*)d_in[4];
  const float* enc_b    = (const float*)d_in[5];
  const float* dec_Wih0 = (const float*)d_in[6];
  const float* dec_WihR = (const float*)d_in[7];
  const float* dec_Whh  = (const float*)d_in[8];
  const float* dec_b    = (const float*)d_in[9];
  const float* fc_W     = (const float*)d_in[10];
  const float* fc_b     = (const float*)d_in[11];

  char* ws = (char*)d_ws;
  _Float16* encw   = (_Float16*)(ws + OFF_ENCW);
  _Float16* decw   = (_Float16*)(ws + OFF_DECW);
  _Float16* ring_e = (_Float16*)(ws + OFF_RING_E);
  _Float16* ring_d = (_Float16*)(ws + OFF_RING_D);
  _Float16* oring  = (_Float16*)(ws + OFF_ORING);
  _Float16* h_enc  = (_Float16*)(ws + OFF_HENC);
  float*    c_enc  = (float*)(ws + OFF_CENC);
  int*      flags  = (int*)(ws + OFF_FLAGS);
  int*      rings  = (int*)(ws + OFF_RING_E);
  float*    outp   = (float*)d_out;

  prep_weights<<<4096, 256, 0, stream>>>(enc_Wih0, enc_WihR, enc_Whh,
                                         dec_Wih0, dec_WihR, dec_Whh, fc_W,
                                         encw, decw, rings, flags);
  enc_pipe<<<256, 512, 0, stream>>>(x, encw, enc_b, ring_e, h_enc, c_enc, flags);
  dec_pipe<<<256, 512, 0, stream>>>(x, decw, dec_b, fc_b, ring_d, oring,
                                    h_enc, c_enc, flags, outp);
}